// Round 11
// baseline (353.227 us; speedup 1.0000x reference)
//
#include <hip/hip_runtime.h>
#include <hip/hip_bf16.h>

// JetGNN: 2-layer SAGEConv(mean) + ReLU + global_mean_pool + Linear(64->2)
// R1-R21: scan/CSR/pool/agg/MFMA ladder (see git log). 355.7us R21.
// R22-R28: fusion arc; fused2 gather pinned ~2 TB/s vs 3.46 split.
// R29: pool de-atomicized (LDS + boundary atomics): fused2 115->99. 344.6.
// R30: layer-2 re-split regression 361.9; exposed fused1=65.8, per-edge
//      rate invariant: 1-pass structures ~50 G-edge/s, 2-pass ~32.
// R31: wave-autonomous (no block barrier): fused2 99->96.3, total 337.0.
//      Barrier was NOT the cost (~3us). Invariant stands: intra-wave pass
//      serialization (8 lanes/node -> 2 serial passes per wave at DIN=64,
//      full drain between) is the one constant in every slow variant.
// R32: 512-thread fused2. Gather = EXACT split shape: node=tid>>3,
//      part=tid&7, ONE pass, wave covers 8 nodes then barriers (cheap,
//      R31-measured). MFMA: wave-pairs split a 16-row tile by col halves
//      (acc[2]). Pool epilogue = R29. fused1 (256-thr, 1-pass) untouched.

#define WS_ALIGN 64
#define EPB 4096          // edges per block in bucket_scatter (256 thr x 16)
#define BSHIFT 8          // 256 nodes per bucket
#define BNODES 256
#define BCAP 6144         // region capacity (mean 4096, sd 64, +32 sigma)
#define MAXNB 1024

typedef short bf16x8 __attribute__((ext_vector_type(8)));
typedef float f32x4 __attribute__((ext_vector_type(4)));

__device__ inline unsigned short f2bf(float f) {   // RNE f32->bf16 (finite inputs)
    unsigned u = __float_as_uint(f);
    return (unsigned short)((u + 0x7fffu + ((u >> 16) & 1u)) >> 16);
}

__device__ inline void acc8(const uint4 u, float* a) {  // 8 bf16 -> fp32 accumulate
    a[0] += __uint_as_float(u.x << 16);
    a[1] += __uint_as_float(u.x & 0xffff0000u);
    a[2] += __uint_as_float(u.y << 16);
    a[3] += __uint_as_float(u.y & 0xffff0000u);
    a[4] += __uint_as_float(u.z << 16);
    a[5] += __uint_as_float(u.z & 0xffff0000u);
    a[6] += __uint_as_float(u.w << 16);
    a[7] += __uint_as_float(u.w & 0xffff0000u);
}

// ---------- prep: x->bf16 cvt + weight prepack + cursors + pool zero ----------

__global__ void prep_kernel(const float* __restrict__ x, unsigned short* __restrict__ xb,
                            const float* __restrict__ W1_l, const float* __restrict__ W1_r,
                            const float* __restrict__ W2_l, const float* __restrict__ W2_r,
                            unsigned short* __restrict__ whi1, unsigned short* __restrict__ whi2,
                            int* __restrict__ bucketCursor, float* __restrict__ pool,
                            int N, int NB, int G, int total4) {
    const int gid = blockIdx.x * blockDim.x + threadIdx.x;
    if (gid < total4) {
        const float4 v = reinterpret_cast<const float4*>(x)[gid];
        ushort4 o;
        o.x = f2bf(v.x); o.y = f2bf(v.y); o.z = f2bf(v.z); o.w = f2bf(v.w);
        reinterpret_cast<ushort4*>(xb)[gid] = o;
    }
    if (gid < NB) bucketCursor[gid] = gid * BCAP;
    if (gid < G * 64) pool[gid] = 0.0f;     // consumed only by fused2 (later launch)
    if (gid < 64 * 64) {        // whi1: rows [o][k], K=64
        const int o = gid >> 6, k = gid & 63;
        const float v = (k < 32) ? W1_l[o * 32 + k] : W1_r[o * 32 + (k - 32)];
        whi1[gid] = f2bf(v);
    }
    if (gid < 64 * 128) {       // whi2: rows [o][k], K=128
        const int o = gid >> 7, k = gid & 127;
        const float v = (k < 64) ? W2_l[o * 64 + k] : W2_r[o * 64 + (k - 64)];
        whi2[gid] = f2bf(v);
    }
}

// ---------- bucket scatter: edges -> fixed-capacity bucket regions ----------

__global__ __launch_bounds__(256) void bucket_scatter_kernel(const int* __restrict__ src,
                                                             const int* __restrict__ dst,
                                                             int* __restrict__ bucketCursor,
                                                             unsigned* __restrict__ bucketData,
                                                             int E, int NB) {
    __shared__ int hist[MAXNB];
    __shared__ int cur[MAXNB];
    const int t = threadIdx.x;
    for (int i = t; i < MAXNB; i += 256) hist[i] = 0;
    __syncthreads();
    const int eBase = blockIdx.x * EPB + t;
    int s[16], b[16], dl[16];
#pragma unroll
    for (int j = 0; j < 16; ++j) {
        int e = eBase + j * 256;
        if (e < E) {
            int d = dst[e];
            s[j]  = src[e];
            b[j]  = d >> BSHIFT;
            dl[j] = d & (BNODES - 1);
            atomicAdd(&hist[b[j]], 1);
        } else {
            b[j] = -1;
        }
    }
    __syncthreads();
    for (int bb = t; bb < NB; bb += 256)
        if (hist[bb] > 0) cur[bb] = atomicAdd(&bucketCursor[bb], hist[bb]);
    __syncthreads();
#pragma unroll
    for (int j = 0; j < 16; ++j) {
        if (b[j] >= 0) {
            int pos = atomicAdd(&cur[b[j]], 1);
            if (pos < (b[j] + 1) * BCAP)     // overflow guard (statistically never)
                bucketData[pos] = ((unsigned)s[j] << BSHIFT) | (unsigned)dl[j];
        }
    }
}

// one block per bucket (256 nodes): LDS deg hist over its region -> scan ->
// offs/offe; scatter pass into the region (dense, single-XCD write-back)
__global__ __launch_bounds__(256) void csr_build_kernel(const unsigned* __restrict__ bucketData,
                                                        const int* __restrict__ bucketCursor,
                                                        int* __restrict__ offs,
                                                        int* __restrict__ offe,
                                                        int* __restrict__ csr_src,
                                                        int N) {
    __shared__ int cnt[BNODES];
    __shared__ int sscan[BNODES];
    __shared__ int cur[BNODES];
    const int t   = threadIdx.x;
    const int bkt = blockIdx.x;
    const int nodeBase = bkt << BSHIFT;
    const int regionBase = bkt * BCAP;
    const int count = min(bucketCursor[bkt] - regionBase, BCAP);
    cnt[t] = 0;
    __syncthreads();
    for (int k = regionBase + t; k < regionBase + count; k += 256)
        atomicAdd(&cnt[bucketData[k] & (BNODES - 1)], 1);
    __syncthreads();
    int v0 = cnt[t];
    sscan[t] = v0;
    __syncthreads();
    for (int off = 1; off < 256; off <<= 1) {
        int v = (t >= off) ? sscan[t - off] : 0;
        __syncthreads();
        sscan[t] += v;
        __syncthreads();
    }
    const int excl = sscan[t] - v0;
    cur[t] = excl;
    const int node = nodeBase + t;
    if (node < N) {
        offs[node] = regionBase + excl;
        offe[node] = regionBase + excl + v0;
    }
    __syncthreads();
    for (int k = regionBase + t; k < regionBase + count; k += 256) {
        const unsigned v = bucketData[k];
        const int d = (int)(v & (BNODES - 1));
        const int pos = regionBase + atomicAdd(&cur[d], 1);
        csr_src[pos] = (int)(v >> BSHIFT);
    }
}

// ---------- layer 1: wave-autonomous fused gather + MFMA (DIN=32) ----------
// 256 thr, 4 waves x 16 rows, 1 gather pass (4 lanes/node), zero barriers.

template <int DIN>
__launch_bounds__(256)
__global__ void fused_l1_kernel(const unsigned short* __restrict__ featb,
                                const unsigned short* __restrict__ whi,
                                const float* __restrict__ bias,
                                const int* __restrict__ csr_src,
                                const int* __restrict__ offs,
                                const int* __restrict__ offe,
                                unsigned short* __restrict__ houtb,
                                int N, int nSteps) {
    constexpr int K   = 2 * DIN;      // 64
    constexpr int STR = K + 8;        // 72
    constexpr int D8  = DIN / 8;      // 4
    __shared__ unsigned short A_s[64 * STR];
    const int tid  = threadIdx.x;
    const int lane = tid & 63;
    const int wave = tid >> 6;
    const int nodeBase = blockIdx.x * 64;
    const int rowBase  = wave * 16;

    // self features into k [DIN, 2*DIN) of wave rows
    for (int i = lane; i < 16 * D8; i += 64) {
        const int row = rowBase + i / D8, q = i % D8;
        const int n = min(nodeBase + row, N - 1);
        const uint4 u = *reinterpret_cast<const uint4*>(featb + (size_t)n * DIN + q * 8);
        *reinterpret_cast<uint4*>(&A_s[row * STR + DIN + q * 8]) = u;
    }
    // gather-mean into k [0, DIN): D8 lanes/node, 1 uint4/edge, ONE pass
    {
        const int part = lane % D8;
        const int row  = rowBase + lane / D8;      // 16 nodes/wave, 1 pass
        const int n = nodeBase + row;
        const uint4* base = reinterpret_cast<const uint4*>(featb);
        unsigned short* dp = &A_s[row * STR + part * 8];
        if (n < N) {
            const int beg = offs[n];
            const int end = offe[n];
            float a[8] = {0.f, 0.f, 0.f, 0.f, 0.f, 0.f, 0.f, 0.f};
            int k = beg;
            for (; k + 8 <= end; k += 8) {
                int s[8];
#pragma unroll
                for (int j = 0; j < 8; ++j) s[j] = csr_src[k + j];
                uint4 u[8];
#pragma unroll
                for (int j = 0; j < 8; ++j) u[j] = base[(size_t)s[j] * D8 + part];
#pragma unroll
                for (int j = 0; j < 8; ++j) acc8(u[j], a);
            }
            for (; k + 4 <= end; k += 4) {
                const int s0 = csr_src[k + 0];
                const int s1 = csr_src[k + 1];
                const int s2 = csr_src[k + 2];
                const int s3 = csr_src[k + 3];
                const uint4 u0 = base[(size_t)s0 * D8 + part];
                const uint4 u1 = base[(size_t)s1 * D8 + part];
                const uint4 u2 = base[(size_t)s2 * D8 + part];
                const uint4 u3 = base[(size_t)s3 * D8 + part];
                acc8(u0, a); acc8(u1, a); acc8(u2, a); acc8(u3, a);
            }
            for (; k < end; ++k) {
                const uint4 u = base[(size_t)csr_src[k] * D8 + part];
                acc8(u, a);
            }
            const float inv = 1.0f / fmaxf((float)(end - beg), 1.0f);
            ushort4 lo4, hi4;
            lo4.x = f2bf(a[0] * inv); lo4.y = f2bf(a[1] * inv);
            lo4.z = f2bf(a[2] * inv); lo4.w = f2bf(a[3] * inv);
            hi4.x = f2bf(a[4] * inv); hi4.y = f2bf(a[5] * inv);
            hi4.z = f2bf(a[6] * inv); hi4.w = f2bf(a[7] * inv);
            *reinterpret_cast<ushort4*>(dp)     = lo4;
            *reinterpret_cast<ushort4*>(dp + 4) = hi4;
        } else {
            const ushort4 z = {0, 0, 0, 0};
            *reinterpret_cast<ushort4*>(dp)     = z;
            *reinterpret_cast<ushort4*>(dp + 4) = z;
        }
    }

    // wave-sync only (rows are wave-private); sched_barrier pins (rule 18)
    asm volatile("s_waitcnt lgkmcnt(0)" ::: "memory");
    __builtin_amdgcn_sched_barrier(0);

    const int lr = lane & 15;
    const int q  = lane >> 4;
    f32x4 acc[4];
#pragma unroll
    for (int t = 0; t < 4; ++t) {
        const float b = bias[t * 16 + lr];
        acc[t] = (f32x4){b, b, b, b};
    }
    const unsigned short* Arow = &A_s[(rowBase + lr) * STR + q * 8];
    const unsigned short* Brow = whi + (size_t)lr * K + q * 8;
    for (int s = 0; s < nSteps; ++s) {
        const bf16x8 af = *reinterpret_cast<const bf16x8*>(Arow + s * 32);
#pragma unroll
        for (int t = 0; t < 4; ++t) {
            const bf16x8 bh = *reinterpret_cast<const bf16x8*>(
                Brow + (size_t)t * 16 * K + s * 32);
            acc[t] = __builtin_amdgcn_mfma_f32_16x16x32_bf16(af, bh, acc[t], 0, 0, 0);
        }
    }
    for (int reg = 0; reg < 4; ++reg) {
        const int n = nodeBase + rowBase + q * 4 + reg;
        if (n >= N) break;
#pragma unroll
        for (int t = 0; t < 4; ++t)
            houtb[(size_t)n * 64 + t * 16 + lr] = f2bf(fmaxf(acc[t][reg], 0.0f));
    }
}

// ---------- layer 2: 512-thr fused gather + MFMA + pool (DIN=64) ----------
// Gather = split shape: node=tid>>3, part=tid&7, ONE pass, 8 nodes/wave.
// One barrier. MFMA: wave-pair per 16-row tile, col halves (acc[2]).

__launch_bounds__(512)
__global__ void fused_l2_pool_kernel(const unsigned short* __restrict__ featb,
                                     const unsigned short* __restrict__ whi,
                                     const float* __restrict__ bias,
                                     const int* __restrict__ csr_src,
                                     const int* __restrict__ offs,
                                     const int* __restrict__ offe,
                                     const int* __restrict__ batch,
                                     float* __restrict__ pool_sum,
                                     int N, int nSteps) {
    constexpr int DIN = 64;
    constexpr int K   = 2 * DIN;      // 128
    constexpr int STR = K + 8;        // 136
    constexpr int D8  = DIN / 8;      // 8
    __shared__ unsigned short A_s[64 * STR];
    __shared__ float poolLds[16 * 65];
    const int tid  = threadIdx.x;     // 0..511
    const int lane = tid & 63;
    const int wave = tid >> 6;        // 0..7
    const int nodeBase = blockIdx.x * 64;

    for (int i = tid; i < 16 * 65; i += 512) poolLds[i] = 0.0f;

    // self features into k [DIN, 2*DIN): 512 items (row = i>>3, q = i&7)
    {
        const int row = tid >> 3, q = tid & 7;
        const int n = min(nodeBase + row, N - 1);
        const uint4 u = *reinterpret_cast<const uint4*>(featb + (size_t)n * DIN + q * 8);
        *reinterpret_cast<uint4*>(&A_s[row * STR + DIN + q * 8]) = u;
    }

    // gather-mean into k [0, DIN): split shape -- node=tid>>3, part=tid&7,
    // one pass over all 64 nodes (8 nodes per wave).
    {
        const int row  = tid >> 3;
        const int part = tid & 7;
        const int n = nodeBase + row;
        const uint4* base = reinterpret_cast<const uint4*>(featb);
        unsigned short* dp = &A_s[row * STR + part * 8];
        if (n < N) {
            const int beg = offs[n];
            const int end = offe[n];
            float a[8] = {0.f, 0.f, 0.f, 0.f, 0.f, 0.f, 0.f, 0.f};
            int k = beg;
            for (; k + 8 <= end; k += 8) {       // 8 uint4 in flight
                int s[8];
#pragma unroll
                for (int j = 0; j < 8; ++j) s[j] = csr_src[k + j];
                uint4 u[8];
#pragma unroll
                for (int j = 0; j < 8; ++j) u[j] = base[(size_t)s[j] * D8 + part];
#pragma unroll
                for (int j = 0; j < 8; ++j) acc8(u[j], a);
            }
            for (; k + 4 <= end; k += 4) {
                const int s0 = csr_src[k + 0];
                const int s1 = csr_src[k + 1];
                const int s2 = csr_src[k + 2];
                const int s3 = csr_src[k + 3];
                const uint4 u0 = base[(size_t)s0 * D8 + part];
                const uint4 u1 = base[(size_t)s1 * D8 + part];
                const uint4 u2 = base[(size_t)s2 * D8 + part];
                const uint4 u3 = base[(size_t)s3 * D8 + part];
                acc8(u0, a); acc8(u1, a); acc8(u2, a); acc8(u3, a);
            }
            for (; k < end; ++k) {
                const uint4 u = base[(size_t)csr_src[k] * D8 + part];
                acc8(u, a);
            }
            const float inv = 1.0f / fmaxf((float)(end - beg), 1.0f);
            ushort4 lo4, hi4;
            lo4.x = f2bf(a[0] * inv); lo4.y = f2bf(a[1] * inv);
            lo4.z = f2bf(a[2] * inv); lo4.w = f2bf(a[3] * inv);
            hi4.x = f2bf(a[4] * inv); hi4.y = f2bf(a[5] * inv);
            hi4.z = f2bf(a[6] * inv); hi4.w = f2bf(a[7] * inv);
            *reinterpret_cast<ushort4*>(dp)     = lo4;
            *reinterpret_cast<ushort4*>(dp + 4) = hi4;
        } else {
            const ushort4 z = {0, 0, 0, 0};
            *reinterpret_cast<ushort4*>(dp)     = z;
            *reinterpret_cast<ushort4*>(dp + 4) = z;
        }
    }
    __syncthreads();   // cheap (R31-measured ~3us); covered by 4 blocks/CU

    // MFMA: tile tg = wave>>1 (16 rows), col half = wave&1 (2 t-groups)
    const int tg      = wave >> 1;
    const int colHalf = wave & 1;
    const int rowBase = tg * 16;
    const int lr = lane & 15;
    const int q  = lane >> 4;
    f32x4 acc[2];
#pragma unroll
    for (int tt = 0; tt < 2; ++tt) {
        const float b = bias[(colHalf * 2 + tt) * 16 + lr];
        acc[tt] = (f32x4){b, b, b, b};
    }
    const unsigned short* Arow = &A_s[(rowBase + lr) * STR + q * 8];
    const unsigned short* Brow = whi + (size_t)lr * K + q * 8;
    for (int s = 0; s < nSteps; ++s) {    // runtime: no full unroll (R11)
        const bf16x8 af = *reinterpret_cast<const bf16x8*>(Arow + s * 32);
#pragma unroll
        for (int tt = 0; tt < 2; ++tt) {
            const bf16x8 bh = *reinterpret_cast<const bf16x8*>(
                Brow + (size_t)(colHalf * 2 + tt) * 16 * K + s * 32);
            acc[tt] = __builtin_amdgcn_mfma_f32_16x16x32_bf16(af, bh, acc[tt], 0, 0, 0);
        }
    }

    // pool epilogue: D row = q*4+reg, col = (colHalf*2+tt)*16 + lr
    {
        const int g0 = batch[nodeBase];
        float ag[2] = {0.f, 0.f};
        int gcur = -1;
        auto flush_run = [&](int g) {
            const int r = g - g0;
            if (r < 16) {
#pragma unroll
                for (int tt = 0; tt < 2; ++tt)
                    atomicAdd(&poolLds[r * 65 + (colHalf * 2 + tt) * 16 + lr], ag[tt]);
            } else {       // statistically never (graphs avg ~50 nodes)
#pragma unroll
                for (int tt = 0; tt < 2; ++tt)
                    atomicAdd(&pool_sum[(size_t)g * 64 + (colHalf * 2 + tt) * 16 + lr],
                              ag[tt]);
            }
        };
        for (int reg = 0; reg < 4; ++reg) {
            const int n = nodeBase + rowBase + q * 4 + reg;
            if (n >= N) break;
            const int g = batch[n];              // sorted
            if (g != gcur) {
                if (gcur >= 0) flush_run(gcur);
                gcur = g;
                ag[0] = ag[1] = 0.f;
            }
#pragma unroll
            for (int tt = 0; tt < 2; ++tt)
                ag[tt] += fmaxf(acc[tt][reg], 0.0f);
        }
        if (gcur >= 0) flush_run(gcur);
        __syncthreads();
        // interior rows sole-writer -> plain store (pool pre-zeroed);
        // boundary rows (r==0, r==S-1) -> global atomicAdd.
        const int glast = batch[min(nodeBase + 63, N - 1)];
        const int S = min(glast - g0 + 1, 16);
        for (int i = tid; i < S * 64; i += 512) {
            const int r = i >> 6, c = i & 63;
            const float v = poolLds[r * 65 + c];
            float* dstp = &pool_sum[(size_t)(g0 + r) * 64 + c];
            if (r == 0 || r == S - 1) atomicAdd(dstp, v);
            else *dstp = v;
        }
    }
}

// ---------- head: per-graph count via binary search over sorted batch ----------

__device__ inline int lower_bound_batch(const int* __restrict__ batch, int N, int key) {
    int lo = 0, hi = N;
    while (lo < hi) {
        const int mid = (lo + hi) >> 1;
        if (batch[mid] < key) lo = mid + 1; else hi = mid;
    }
    return lo;
}

__global__ void final_kernel(const float* __restrict__ pool_sum,
                             const int* __restrict__ batch,
                             const float* __restrict__ W_lin,
                             const float* __restrict__ b_lin,
                             float* __restrict__ out, int G, int N) {
    int t = blockIdx.x * blockDim.x + threadIdx.x;
    if (t >= G * 2) return;
    int g = t >> 1, o = t & 1;
    const int c0 = lower_bound_batch(batch, N, g);
    const int c1 = lower_bound_batch(batch, N, g + 1);
    float inv = 1.0f / fmaxf((float)(c1 - c0), 1.0f);
    float acc = b_lin[o];
#pragma unroll
    for (int c = 0; c < 64; ++c)
        acc = fmaf(pool_sum[(size_t)g * 64 + c] * inv, W_lin[o * 64 + c], acc);
    out[t] = acc;
}

extern "C" void kernel_launch(void* const* d_in, const int* in_sizes, int n_in,
                              void* d_out, int out_size, void* d_ws, size_t ws_size,
                              hipStream_t stream) {
    const float* x     = (const float*)d_in[0];
    const int*   ei    = (const int*)d_in[1];
    const int*   batch = (const int*)d_in[2];
    const float* W1_l  = (const float*)d_in[3];
    const float* b1    = (const float*)d_in[4];
    const float* W1_r  = (const float*)d_in[5];
    const float* W2_l  = (const float*)d_in[6];
    const float* b2    = (const float*)d_in[7];
    const float* W2_r  = (const float*)d_in[8];
    const float* W_lin = (const float*)d_in[9];
    const float* b_lin = (const float*)d_in[10];

    const int N = in_sizes[0] / 32;
    const int E = in_sizes[1] / 2;
    const int G = out_size / 2;
    const int* src = ei;
    const int* dst = ei + E;
    const int NB = (N + BNODES - 1) >> BSHIFT;   // 782 for N=200000

    char* p = (char*)d_ws;
    auto carve = [&](size_t bytes) -> void* {
        void* r = (void*)p;
        p += (bytes + (WS_ALIGN - 1)) / WS_ALIGN * WS_ALIGN;
        return r;
    };
    int*            bucketCursor = (int*)carve((size_t)MAXNB * 4);
    unsigned*       bucketData   = (unsigned*)carve((size_t)NB * BCAP * 4);
    int*            offs         = (int*)carve((size_t)N * 4);
    int*            offe         = (int*)carve((size_t)N * 4);
    int*            csr_src      = (int*)carve((size_t)NB * BCAP * 4);
    unsigned short* xb           = (unsigned short*)carve((size_t)N * 32 * 2);
    unsigned short* h1b          = (unsigned short*)carve((size_t)N * 64 * 2);
    unsigned short* whi1         = (unsigned short*)carve(64 * 64 * 2);
    unsigned short* whi2         = (unsigned short*)carve(64 * 128 * 2);
    float*          pool         = (float*)carve((size_t)G * 64 * 4);
    float*          out          = (float*)d_out;

    const int TB = 256;
    const int total4 = N * 32 / 4;
    prep_kernel<<<(total4 + TB - 1) / TB, TB, 0, stream>>>(
        x, xb, W1_l, W1_r, W2_l, W2_r, whi1, whi2, bucketCursor, pool,
        N, NB, G, total4);
    bucket_scatter_kernel<<<(E + EPB - 1) / EPB, TB, 0, stream>>>(src, dst, bucketCursor,
                                                                  bucketData, E, NB);
    csr_build_kernel<<<NB, TB, 0, stream>>>(bucketData, bucketCursor, offs, offe, csr_src, N);

    // layer 1: fused gather-mean(xb) + MFMA 32->64 + relu -> h1b (bf16)
    fused_l1_kernel<32><<<(N + 63) / 64, TB, 0, stream>>>(
        xb, whi1, b1, csr_src, offs, offe, h1b, N, 2);

    // layer 2: 512-thr fused gather-mean(h1b) + MFMA 64->64 + relu + pool
    fused_l2_pool_kernel<<<(N + 63) / 64, 512, 0, stream>>>(
        h1b, whi2, b2, csr_src, offs, offe, batch, pool, N, 4);

    final_kernel<<<(G * 2 + TB - 1) / TB, TB, 0, stream>>>(pool, batch, W_lin, b_lin,
                                                           out, G, N);
}

// Round 12
// 324.691 us; speedup vs baseline: 1.0879x; 1.0879x over previous
//
#include <hip/hip_runtime.h>
#include <hip/hip_bf16.h>

// JetGNN: 2-layer SAGEConv(mean) + ReLU + global_mean_pool + Linear(64->2)
// R1-R21: scan/CSR/pool/agg/MFMA ladder (see git log). 355.7us R21.
// R22-R28: fusion arc; fused2 pinned ~2 TB/s vs 3.46 split.
// R29: pool de-atomicized: fused2 115->99, total 344.6.
// R30: re-split regression 361.9 (split l2 = ~116 end-to-end).
// R31: wave-autonomous fused2 96.3, total 337.0 (best).
// R32: 1-pass 512-thr fused2 108 -- REGRESSION. Fused2 floor ~96 is robust
//      across 5 structures; stop iterating there.
// R33: layers = R31 verbatim. Attack preprocessing (~130-140us by
//      subtraction, <1 TB/s = overhead-bound):
//      (1) bucket_scatter: LDS counting-sort by bucket + precomputed global
//          addresses -> writeout in sorted order (runs avg 5.2 words) =
//          wave-coalesced, ~4x fewer write txns vs 3.2M scattered 4B.
//      (2) csr_build: region staged in LDS once (kills 2nd global read),
//          counting-sort by dstLocal in LDS, csr_src written as one
//          sequential coalesced stream per block.

#define WS_ALIGN 64
#define EPB 4096          // edges per block in bucket_scatter (256 thr x 16)
#define BSHIFT 8          // 256 nodes per bucket
#define BNODES 256
#define BCAP 6144         // region capacity (mean 4096, sd 64, +32 sigma)
#define MAXNB 1024

typedef short bf16x8 __attribute__((ext_vector_type(8)));
typedef float f32x4 __attribute__((ext_vector_type(4)));

__device__ inline unsigned short f2bf(float f) {   // RNE f32->bf16 (finite inputs)
    unsigned u = __float_as_uint(f);
    return (unsigned short)((u + 0x7fffu + ((u >> 16) & 1u)) >> 16);
}

__device__ inline void acc8(const uint4 u, float* a) {  // 8 bf16 -> fp32 accumulate
    a[0] += __uint_as_float(u.x << 16);
    a[1] += __uint_as_float(u.x & 0xffff0000u);
    a[2] += __uint_as_float(u.y << 16);
    a[3] += __uint_as_float(u.y & 0xffff0000u);
    a[4] += __uint_as_float(u.z << 16);
    a[5] += __uint_as_float(u.z & 0xffff0000u);
    a[6] += __uint_as_float(u.w << 16);
    a[7] += __uint_as_float(u.w & 0xffff0000u);
}

// ---------- prep: x->bf16 cvt + weight prepack + cursors + pool zero ----------

__global__ void prep_kernel(const float* __restrict__ x, unsigned short* __restrict__ xb,
                            const float* __restrict__ W1_l, const float* __restrict__ W1_r,
                            const float* __restrict__ W2_l, const float* __restrict__ W2_r,
                            unsigned short* __restrict__ whi1, unsigned short* __restrict__ whi2,
                            int* __restrict__ bucketCursor, float* __restrict__ pool,
                            int N, int NB, int G, int total4) {
    const int gid = blockIdx.x * blockDim.x + threadIdx.x;
    if (gid < total4) {
        const float4 v = reinterpret_cast<const float4*>(x)[gid];
        ushort4 o;
        o.x = f2bf(v.x); o.y = f2bf(v.y); o.z = f2bf(v.z); o.w = f2bf(v.w);
        reinterpret_cast<ushort4*>(xb)[gid] = o;
    }
    if (gid < NB) bucketCursor[gid] = gid * BCAP;
    if (gid < G * 64) pool[gid] = 0.0f;     // consumed only by fused2 (later launch)
    if (gid < 64 * 64) {        // whi1: rows [o][k], K=64
        const int o = gid >> 6, k = gid & 63;
        const float v = (k < 32) ? W1_l[o * 32 + k] : W1_r[o * 32 + (k - 32)];
        whi1[gid] = f2bf(v);
    }
    if (gid < 64 * 128) {       // whi2: rows [o][k], K=128
        const int o = gid >> 7, k = gid & 127;
        const float v = (k < 64) ? W2_l[o * 64 + k] : W2_r[o * 64 + (k - 64)];
        whi2[gid] = f2bf(v);
    }
}

// ---------- bucket scatter: LDS counting-sort by bucket, coalesced writeout ----

__global__ __launch_bounds__(256) void bucket_scatter_kernel(const int* __restrict__ src,
                                                             const int* __restrict__ dst,
                                                             int* __restrict__ bucketCursor,
                                                             unsigned* __restrict__ bucketData,
                                                             int E, int NB) {
    __shared__ int hist[MAXNB];
    __shared__ int lofs[MAXNB];
    __shared__ int lcur[MAXNB];
    __shared__ int gbase[MAXNB];
    __shared__ int sscan[256];
    __shared__ unsigned staged[EPB];   // records sorted by bucket
    __shared__ int gaddr[EPB];         // precomputed global position (-1 = drop)
    const int t = threadIdx.x;
    for (int i = t; i < MAXNB; i += 256) hist[i] = 0;
    __syncthreads();
    const int eBase = blockIdx.x * EPB + t;
    int bkt[16]; unsigned rec[16];
#pragma unroll
    for (int j = 0; j < 16; ++j) {
        const int e = eBase + j * 256;
        if (e < E) {
            const int d = dst[e];
            bkt[j] = d >> BSHIFT;
            rec[j] = ((unsigned)src[e] << BSHIFT) | (unsigned)(d & (BNODES - 1));
            atomicAdd(&hist[bkt[j]], 1);
        } else {
            bkt[j] = -1;
        }
    }
    __syncthreads();
    // exclusive scan of hist[0..1024) with 256 threads (4 entries each)
    const int b4 = t * 4;
    const int h0 = hist[b4], h1 = hist[b4 + 1], h2 = hist[b4 + 2], h3 = hist[b4 + 3];
    const int tsum = h0 + h1 + h2 + h3;
    sscan[t] = tsum;
    __syncthreads();
    for (int off = 1; off < 256; off <<= 1) {
        const int v = (t >= off) ? sscan[t - off] : 0;
        __syncthreads();
        sscan[t] += v;
        __syncthreads();
    }
    const int excl = sscan[t] - tsum;
    lofs[b4]     = excl;
    lofs[b4 + 1] = excl + h0;
    lofs[b4 + 2] = excl + h0 + h1;
    lofs[b4 + 3] = excl + h0 + h1 + h2;
    lcur[b4]     = lofs[b4];
    lcur[b4 + 1] = lofs[b4 + 1];
    lcur[b4 + 2] = lofs[b4 + 2];
    lcur[b4 + 3] = lofs[b4 + 3];
    // reserve global runs (one atomic per non-empty bucket per block)
    for (int bb = t; bb < NB; bb += 256)
        if (hist[bb] > 0) gbase[bb] = atomicAdd(&bucketCursor[bb], hist[bb]);
    __syncthreads();
    // place into bucket-sorted LDS order, precompute global addresses
#pragma unroll
    for (int j = 0; j < 16; ++j) {
        if (bkt[j] >= 0) {
            const int b = bkt[j];
            const int lp = atomicAdd(&lcur[b], 1);
            staged[lp] = rec[j];
            const int gp = gbase[b] + (lp - lofs[b]);
            gaddr[lp] = (gp < (b + 1) * BCAP) ? gp : -1;  // overflow guard
        }
    }
    __syncthreads();
    // writeout in sorted order: consecutive i -> consecutive addrs within runs
    const int cnt = min(EPB, E - blockIdx.x * EPB);
    for (int i = t; i < cnt; i += 256) {
        const int p = gaddr[i];
        if (p >= 0) bucketData[p] = staged[i];
    }
}

// one block per bucket (256 nodes): region staged in LDS, counting-sort by
// dstLocal in LDS, csr_src written as one sequential coalesced stream.
__global__ __launch_bounds__(256) void csr_build_kernel(const unsigned* __restrict__ bucketData,
                                                        const int* __restrict__ bucketCursor,
                                                        int* __restrict__ offs,
                                                        int* __restrict__ offe,
                                                        int* __restrict__ csr_src,
                                                        int N) {
    __shared__ unsigned ldsIn[BCAP];    // 24KB
    __shared__ unsigned ldsOut[BCAP];   // 24KB
    __shared__ int cnt[BNODES];
    __shared__ int sscan[BNODES];
    __shared__ int cur[BNODES];
    const int t   = threadIdx.x;
    const int bkt = blockIdx.x;
    const int nodeBase = bkt << BSHIFT;
    const int regionBase = bkt * BCAP;
    const int count = min(bucketCursor[bkt] - regionBase, BCAP);
    cnt[t] = 0;
    __syncthreads();
    // stage region (coalesced read) + histogram from LDS
    for (int k = t; k < count; k += 256) {
        const unsigned v = bucketData[regionBase + k];
        ldsIn[k] = v;
        atomicAdd(&cnt[v & (BNODES - 1)], 1);
    }
    __syncthreads();
    const int v0 = cnt[t];
    sscan[t] = v0;
    __syncthreads();
    for (int off = 1; off < 256; off <<= 1) {
        const int v = (t >= off) ? sscan[t - off] : 0;
        __syncthreads();
        sscan[t] += v;
        __syncthreads();
    }
    const int excl = sscan[t] - v0;
    cur[t] = excl;
    const int node = nodeBase + t;
    if (node < N) {
        offs[node] = regionBase + excl;
        offe[node] = regionBase + excl + v0;
    }
    __syncthreads();
    // counting-sort scatter inside LDS
    for (int k = t; k < count; k += 256) {
        const unsigned v = ldsIn[k];
        const int p = atomicAdd(&cur[v & (BNODES - 1)], 1);
        ldsOut[p] = v >> BSHIFT;
    }
    __syncthreads();
    // sequential coalesced write
    for (int k = t; k < count; k += 256)
        csr_src[regionBase + k] = (int)ldsOut[k];
}

// ---------- wave-autonomous fused gather-mean + MFMA + relu (+pool) ----------
// R31 verbatim: per block 64 nodes = 4 waves x 16-row tiles; wave-private
// gather (D8 lanes/node, 1 uint4/edge), lgkmcnt wave-sync (no block barrier
// in the main path), MFMA vs B (global, L2-hot). POOL: 16-row LDS pool +
// boundary-only global atomics; r>=16 falls back to direct global atomic.

template <int DIN, bool POOL>
__launch_bounds__(256)
__global__ void fused_agg_mfma_kernel(const unsigned short* __restrict__ featb,
                                      const unsigned short* __restrict__ whi,
                                      const float* __restrict__ bias,
                                      const int* __restrict__ csr_src,
                                      const int* __restrict__ offs,
                                      const int* __restrict__ offe,
                                      unsigned short* __restrict__ houtb,
                                      const int* __restrict__ batch,
                                      float* __restrict__ pool_sum,
                                      int N, int nSteps) {
    constexpr int K     = 2 * DIN;    // 64 / 128
    constexpr int STR   = K + 8;      // 72 / 136 ushorts, rows 16B-aligned
    constexpr int D8    = DIN / 8;    // uint4 per feature row (4 / 8)
    constexpr int NPW   = 64 / D8;    // nodes gathered per wave pass (16 / 8)
    constexpr int NPASS = 16 / NPW;   // passes to cover wave's 16 rows (1 / 2)
    __shared__ unsigned short A_s[64 * STR];
    __shared__ float poolLds[POOL ? 16 * 65 : 1];   // [graph-row][ch]
    const int tid  = threadIdx.x;
    const int lane = tid & 63;
    const int wave = tid >> 6;
    const int nodeBase = blockIdx.x * 64;
    const int rowBase  = wave * 16;           // wave-owned A_s rows

    if (POOL) {
        for (int i = tid; i < 16 * 65; i += 256) poolLds[i] = 0.0f;
        __syncthreads();   // cheap: pre-gather, all waves arrive together
    }

    // ---- per-wave: self features into k [DIN, 2*DIN) of rows [rowBase,+16) ----
    for (int i = lane; i < 16 * D8; i += 64) {
        const int row = rowBase + i / D8, q = i % D8;
        const int n = min(nodeBase + row, N - 1);
        const uint4 u = *reinterpret_cast<const uint4*>(featb + (size_t)n * DIN + q * 8);
        *reinterpret_cast<uint4*>(&A_s[row * STR + DIN + q * 8]) = u;
    }

    // ---- per-wave: gather-mean into k [0, DIN): D8 lanes/node, 1 uint4/edge ----
    {
        const int part = lane % D8;
        const uint4* base = reinterpret_cast<const uint4*>(featb);
#pragma unroll
        for (int pass = 0; pass < NPASS; ++pass) {
            const int row = rowBase + pass * NPW + lane / D8;
            const int n = nodeBase + row;
            unsigned short* dp = &A_s[row * STR + part * 8];
            if (n < N) {
                const int beg = offs[n];
                const int end = offe[n];
                float a[8] = {0.f, 0.f, 0.f, 0.f, 0.f, 0.f, 0.f, 0.f};
                int k = beg;
                for (; k + 8 <= end; k += 8) {       // 8 uint4 in flight
                    int s[8];
#pragma unroll
                    for (int j = 0; j < 8; ++j) s[j] = csr_src[k + j];
                    uint4 u[8];
#pragma unroll
                    for (int j = 0; j < 8; ++j) u[j] = base[(size_t)s[j] * D8 + part];
#pragma unroll
                    for (int j = 0; j < 8; ++j) acc8(u[j], a);
                }
                for (; k + 4 <= end; k += 4) {
                    const int s0 = csr_src[k + 0];
                    const int s1 = csr_src[k + 1];
                    const int s2 = csr_src[k + 2];
                    const int s3 = csr_src[k + 3];
                    const uint4 u0 = base[(size_t)s0 * D8 + part];
                    const uint4 u1 = base[(size_t)s1 * D8 + part];
                    const uint4 u2 = base[(size_t)s2 * D8 + part];
                    const uint4 u3 = base[(size_t)s3 * D8 + part];
                    acc8(u0, a); acc8(u1, a); acc8(u2, a); acc8(u3, a);
                }
                for (; k < end; ++k) {
                    const uint4 u = base[(size_t)csr_src[k] * D8 + part];
                    acc8(u, a);
                }
                const float inv = 1.0f / fmaxf((float)(end - beg), 1.0f);
                ushort4 lo4, hi4;
                lo4.x = f2bf(a[0] * inv); lo4.y = f2bf(a[1] * inv);
                lo4.z = f2bf(a[2] * inv); lo4.w = f2bf(a[3] * inv);
                hi4.x = f2bf(a[4] * inv); hi4.y = f2bf(a[5] * inv);
                hi4.z = f2bf(a[6] * inv); hi4.w = f2bf(a[7] * inv);
                *reinterpret_cast<ushort4*>(dp)     = lo4;
                *reinterpret_cast<ushort4*>(dp + 4) = hi4;
            } else {
                const ushort4 z = {0, 0, 0, 0};
                *reinterpret_cast<ushort4*>(dp)     = z;
                *reinterpret_cast<ushort4*>(dp + 4) = z;
            }
        }
    }

    // wave-sync: drain this wave's LDS writes before its ds_reads (no block
    // barrier -- rows are wave-private). sched_barrier pins ordering (rule 18).
    asm volatile("s_waitcnt lgkmcnt(0)" ::: "memory");
    __builtin_amdgcn_sched_barrier(0);

    const int lr = lane & 15;        // A: m (node); B: n (out); D: col (out)
    const int q  = lane >> 4;        // frag k-quad; D row group
    f32x4 acc[4];
#pragma unroll
    for (int t = 0; t < 4; ++t) {
        const float b = bias[t * 16 + lr];
        acc[t] = (f32x4){b, b, b, b};
    }
    const unsigned short* Arow = &A_s[(rowBase + lr) * STR + q * 8];
    const unsigned short* Brow = whi + (size_t)lr * K + q * 8;   // + t*16*K + s*32
    for (int s = 0; s < nSteps; ++s) {    // runtime: no full unroll (R11)
        const bf16x8 af = *reinterpret_cast<const bf16x8*>(Arow + s * 32);
#pragma unroll
        for (int t = 0; t < 4; ++t) {
            const bf16x8 bh = *reinterpret_cast<const bf16x8*>(
                Brow + (size_t)t * 16 * K + s * 32);
            acc[t] = __builtin_amdgcn_mfma_f32_16x16x32_bf16(af, bh, acc[t], 0, 0, 0);
        }
    }

    // D layout: row(node local 16) = q*4 + reg, col(out) = t*16 + lr
    if (POOL) {
        const int g0 = batch[nodeBase];
        float ag[4] = {0.f, 0.f, 0.f, 0.f};
        int gcur = -1;
        auto flush_run = [&](int g) {
            const int r = g - g0;
            if (r < 16) {
#pragma unroll
                for (int t = 0; t < 4; ++t)
                    atomicAdd(&poolLds[r * 65 + t * 16 + lr], ag[t]);
            } else {       // statistically never (graphs avg ~50 nodes)
#pragma unroll
                for (int t = 0; t < 4; ++t)
                    atomicAdd(&pool_sum[(size_t)g * 64 + t * 16 + lr], ag[t]);
            }
        };
        for (int reg = 0; reg < 4; ++reg) {
            const int n = nodeBase + rowBase + q * 4 + reg;
            if (n >= N) break;
            const int g = batch[n];              // sorted
            if (g != gcur) {
                if (gcur >= 0) flush_run(gcur);
                gcur = g;
                ag[0] = ag[1] = ag[2] = ag[3] = 0.f;
            }
#pragma unroll
            for (int t = 0; t < 4; ++t)
                ag[t] += fmaxf(acc[t][reg], 0.0f);
        }
        if (gcur >= 0) flush_run(gcur);
        __syncthreads();
        // flush: interior rows sole-writer -> plain store (pool pre-zeroed);
        // boundary rows (r==0, r==S-1) -> global atomicAdd.
        const int glast = batch[min(nodeBase + 63, N - 1)];
        const int S = min(glast - g0 + 1, 16);
        for (int i = tid; i < S * 64; i += 256) {
            const int r = i >> 6, c = i & 63;
            const float v = poolLds[r * 65 + c];
            float* dstp = &pool_sum[(size_t)(g0 + r) * 64 + c];
            if (r == 0 || r == S - 1) atomicAdd(dstp, v);
            else *dstp = v;
        }
    } else {
        for (int reg = 0; reg < 4; ++reg) {
            const int n = nodeBase + rowBase + q * 4 + reg;
            if (n >= N) break;
#pragma unroll
            for (int t = 0; t < 4; ++t)
                houtb[(size_t)n * 64 + t * 16 + lr] = f2bf(fmaxf(acc[t][reg], 0.0f));
        }
    }
}

// ---------- head: per-graph count via binary search over sorted batch ----------

__device__ inline int lower_bound_batch(const int* __restrict__ batch, int N, int key) {
    int lo = 0, hi = N;
    while (lo < hi) {
        const int mid = (lo + hi) >> 1;
        if (batch[mid] < key) lo = mid + 1; else hi = mid;
    }
    return lo;
}

__global__ void final_kernel(const float* __restrict__ pool_sum,
                             const int* __restrict__ batch,
                             const float* __restrict__ W_lin,
                             const float* __restrict__ b_lin,
                             float* __restrict__ out, int G, int N) {
    int t = blockIdx.x * blockDim.x + threadIdx.x;
    if (t >= G * 2) return;
    int g = t >> 1, o = t & 1;
    const int c0 = lower_bound_batch(batch, N, g);
    const int c1 = lower_bound_batch(batch, N, g + 1);
    float inv = 1.0f / fmaxf((float)(c1 - c0), 1.0f);
    float acc = b_lin[o];
#pragma unroll
    for (int c = 0; c < 64; ++c)
        acc = fmaf(pool_sum[(size_t)g * 64 + c] * inv, W_lin[o * 64 + c], acc);
    out[t] = acc;
}

extern "C" void kernel_launch(void* const* d_in, const int* in_sizes, int n_in,
                              void* d_out, int out_size, void* d_ws, size_t ws_size,
                              hipStream_t stream) {
    const float* x     = (const float*)d_in[0];
    const int*   ei    = (const int*)d_in[1];
    const int*   batch = (const int*)d_in[2];
    const float* W1_l  = (const float*)d_in[3];
    const float* b1    = (const float*)d_in[4];
    const float* W1_r  = (const float*)d_in[5];
    const float* W2_l  = (const float*)d_in[6];
    const float* b2    = (const float*)d_in[7];
    const float* W2_r  = (const float*)d_in[8];
    const float* W_lin = (const float*)d_in[9];
    const float* b_lin = (const float*)d_in[10];

    const int N = in_sizes[0] / 32;
    const int E = in_sizes[1] / 2;
    const int G = out_size / 2;
    const int* src = ei;
    const int* dst = ei + E;
    const int NB = (N + BNODES - 1) >> BSHIFT;   // 782 for N=200000

    char* p = (char*)d_ws;
    auto carve = [&](size_t bytes) -> void* {
        void* r = (void*)p;
        p += (bytes + (WS_ALIGN - 1)) / WS_ALIGN * WS_ALIGN;
        return r;
    };
    int*            bucketCursor = (int*)carve((size_t)MAXNB * 4);
    unsigned*       bucketData   = (unsigned*)carve((size_t)NB * BCAP * 4);
    int*            offs         = (int*)carve((size_t)N * 4);
    int*            offe         = (int*)carve((size_t)N * 4);
    int*            csr_src      = (int*)carve((size_t)NB * BCAP * 4);
    unsigned short* xb           = (unsigned short*)carve((size_t)N * 32 * 2);
    unsigned short* h1b          = (unsigned short*)carve((size_t)N * 64 * 2);
    unsigned short* whi1         = (unsigned short*)carve(64 * 64 * 2);
    unsigned short* whi2         = (unsigned short*)carve(64 * 128 * 2);
    float*          pool         = (float*)carve((size_t)G * 64 * 4);
    float*          out          = (float*)d_out;

    const int TB = 256;
    const int total4 = N * 32 / 4;
    prep_kernel<<<(total4 + TB - 1) / TB, TB, 0, stream>>>(
        x, xb, W1_l, W1_r, W2_l, W2_r, whi1, whi2, bucketCursor, pool,
        N, NB, G, total4);
    bucket_scatter_kernel<<<(E + EPB - 1) / EPB, TB, 0, stream>>>(src, dst, bucketCursor,
                                                                  bucketData, E, NB);
    csr_build_kernel<<<NB, TB, 0, stream>>>(bucketData, bucketCursor, offs, offe, csr_src, N);

    // layer 1: fused gather-mean(xb) + MFMA 32->64 + relu -> h1b (bf16)
    fused_agg_mfma_kernel<32, false><<<(N + 63) / 64, TB, 0, stream>>>(
        xb, whi1, b1, csr_src, offs, offe, h1b, nullptr, nullptr, N, 2);

    // layer 2: fused gather-mean(h1b) + MFMA 64->64 + relu + pool
    fused_agg_mfma_kernel<64, true><<<(N + 63) / 64, TB, 0, stream>>>(
        h1b, whi2, b2, csr_src, offs, offe, nullptr, batch, pool, N, 4);

    final_kernel<<<(G * 2 + TB - 1) / TB, TB, 0, stream>>>(pool, batch, W_lin, b_lin,
                                                           out, G, N);
}

// Round 13
// 323.556 us; speedup vs baseline: 1.0917x; 1.0035x over previous
//
#include <hip/hip_runtime.h>
#include <hip/hip_bf16.h>

// JetGNN: 2-layer SAGEConv(mean) + ReLU + global_mean_pool + Linear(64->2)
// R1-R21: scan/CSR/pool/agg/MFMA ladder. 355.7us R21.
// R22-R32: fusion arc. fused2 floor ~96us robust across 5 structures.
// R29: LDS pool (WRITE 21.9->1.76MB). R31: wave-autonomous. R33: LDS
//      counting-sort preprocessing -> 324.7us (best).
// R34: (1) persistent tiles: fused2 was 3125 blocks / 1792 resident = 1.74
//      rounds -> ~40% CUs idle in final round. Now grid=1792, block strides
//      tiles. fused1: waves are autonomous (R31) -> per-WAVE tile stride,
//      zero barriers, grid=2048. (2) scatter/csr at 512 thr: one-round
//      residency means runtime = per-block critical path; halve per-thread
//      record count (16->8).

#define WS_ALIGN 64
#define EPB 4096          // edges per block in bucket_scatter (512 thr x 8)
#define BSHIFT 8          // 256 nodes per bucket
#define BNODES 256
#define BCAP 6144         // region capacity (mean 4096, sd 64, +32 sigma)
#define MAXNB 1024

typedef short bf16x8 __attribute__((ext_vector_type(8)));
typedef float f32x4 __attribute__((ext_vector_type(4)));

__device__ inline unsigned short f2bf(float f) {   // RNE f32->bf16 (finite inputs)
    unsigned u = __float_as_uint(f);
    return (unsigned short)((u + 0x7fffu + ((u >> 16) & 1u)) >> 16);
}

__device__ inline void acc8(const uint4 u, float* a) {  // 8 bf16 -> fp32 accumulate
    a[0] += __uint_as_float(u.x << 16);
    a[1] += __uint_as_float(u.x & 0xffff0000u);
    a[2] += __uint_as_float(u.y << 16);
    a[3] += __uint_as_float(u.y & 0xffff0000u);
    a[4] += __uint_as_float(u.z << 16);
    a[5] += __uint_as_float(u.z & 0xffff0000u);
    a[6] += __uint_as_float(u.w << 16);
    a[7] += __uint_as_float(u.w & 0xffff0000u);
}

// ---------- prep: x->bf16 cvt + weight prepack + cursors + pool zero ----------

__global__ void prep_kernel(const float* __restrict__ x, unsigned short* __restrict__ xb,
                            const float* __restrict__ W1_l, const float* __restrict__ W1_r,
                            const float* __restrict__ W2_l, const float* __restrict__ W2_r,
                            unsigned short* __restrict__ whi1, unsigned short* __restrict__ whi2,
                            int* __restrict__ bucketCursor, float* __restrict__ pool,
                            int N, int NB, int G, int total4) {
    const int gid = blockIdx.x * blockDim.x + threadIdx.x;
    if (gid < total4) {
        const float4 v = reinterpret_cast<const float4*>(x)[gid];
        ushort4 o;
        o.x = f2bf(v.x); o.y = f2bf(v.y); o.z = f2bf(v.z); o.w = f2bf(v.w);
        reinterpret_cast<ushort4*>(xb)[gid] = o;
    }
    if (gid < NB) bucketCursor[gid] = gid * BCAP;
    if (gid < G * 64) pool[gid] = 0.0f;     // consumed only by fused2 (later launch)
    if (gid < 64 * 64) {        // whi1: rows [o][k], K=64
        const int o = gid >> 6, k = gid & 63;
        const float v = (k < 32) ? W1_l[o * 32 + k] : W1_r[o * 32 + (k - 32)];
        whi1[gid] = f2bf(v);
    }
    if (gid < 64 * 128) {       // whi2: rows [o][k], K=128
        const int o = gid >> 7, k = gid & 127;
        const float v = (k < 64) ? W2_l[o * 64 + k] : W2_r[o * 64 + (k - 64)];
        whi2[gid] = f2bf(v);
    }
}

// ---------- bucket scatter: 512-thr LDS counting-sort, coalesced writeout ----

__global__ __launch_bounds__(512) void bucket_scatter_kernel(const int* __restrict__ src,
                                                             const int* __restrict__ dst,
                                                             int* __restrict__ bucketCursor,
                                                             unsigned* __restrict__ bucketData,
                                                             int E, int NB) {
    __shared__ int hist[MAXNB];
    __shared__ int lofs[MAXNB];
    __shared__ int lcur[MAXNB];
    __shared__ int gbase[MAXNB];
    __shared__ int sscan[512];
    __shared__ unsigned staged[EPB];   // records sorted by bucket
    __shared__ int gaddr[EPB];         // precomputed global position (-1 = drop)
    const int t = threadIdx.x;
    for (int i = t; i < MAXNB; i += 512) hist[i] = 0;
    __syncthreads();
    const int eBase = blockIdx.x * EPB + t;
    int bkt[8]; unsigned rec[8];
#pragma unroll
    for (int j = 0; j < 8; ++j) {
        const int e = eBase + j * 512;
        if (e < E) {
            const int d = dst[e];
            bkt[j] = d >> BSHIFT;
            rec[j] = ((unsigned)src[e] << BSHIFT) | (unsigned)(d & (BNODES - 1));
            atomicAdd(&hist[bkt[j]], 1);
        } else {
            bkt[j] = -1;
        }
    }
    __syncthreads();
    // exclusive scan of hist[0..1024) with 512 threads (2 entries each)
    const int b2 = t * 2;
    const int h0 = hist[b2], h1 = hist[b2 + 1];
    const int tsum = h0 + h1;
    sscan[t] = tsum;
    __syncthreads();
    for (int off = 1; off < 512; off <<= 1) {
        const int v = (t >= off) ? sscan[t - off] : 0;
        __syncthreads();
        sscan[t] += v;
        __syncthreads();
    }
    const int excl = sscan[t] - tsum;
    lofs[b2]     = excl;
    lofs[b2 + 1] = excl + h0;
    lcur[b2]     = excl;
    lcur[b2 + 1] = excl + h0;
    // reserve global runs (one atomic per non-empty bucket per block)
    for (int bb = t; bb < NB; bb += 512)
        if (hist[bb] > 0) gbase[bb] = atomicAdd(&bucketCursor[bb], hist[bb]);
    __syncthreads();
    // place into bucket-sorted LDS order, precompute global addresses
#pragma unroll
    for (int j = 0; j < 8; ++j) {
        if (bkt[j] >= 0) {
            const int b = bkt[j];
            const int lp = atomicAdd(&lcur[b], 1);
            staged[lp] = rec[j];
            const int gp = gbase[b] + (lp - lofs[b]);
            gaddr[lp] = (gp < (b + 1) * BCAP) ? gp : -1;  // overflow guard
        }
    }
    __syncthreads();
    // writeout in sorted order: consecutive i -> consecutive addrs within runs
    const int cnt = min(EPB, E - blockIdx.x * EPB);
    for (int i = t; i < cnt; i += 512) {
        const int p = gaddr[i];
        if (p >= 0) bucketData[p] = staged[i];
    }
}

// 512-thr, one block per bucket: region staged in LDS, counting-sort by
// dstLocal in LDS, csr_src written as one sequential coalesced stream.
__global__ __launch_bounds__(512) void csr_build_kernel(const unsigned* __restrict__ bucketData,
                                                        const int* __restrict__ bucketCursor,
                                                        int* __restrict__ offs,
                                                        int* __restrict__ offe,
                                                        int* __restrict__ csr_src,
                                                        int N) {
    __shared__ unsigned ldsIn[BCAP];    // 24KB
    __shared__ unsigned ldsOut[BCAP];   // 24KB
    __shared__ int cnt[BNODES];
    __shared__ int sscan[BNODES];
    __shared__ int cur[BNODES];
    const int t   = threadIdx.x;
    const int bkt = blockIdx.x;
    const int nodeBase = bkt << BSHIFT;
    const int regionBase = bkt * BCAP;
    const int count = min(bucketCursor[bkt] - regionBase, BCAP);
    if (t < BNODES) cnt[t] = 0;
    __syncthreads();
    // stage region (coalesced read) + histogram from LDS
    for (int k = t; k < count; k += 512) {
        const unsigned v = bucketData[regionBase + k];
        ldsIn[k] = v;
        atomicAdd(&cnt[v & (BNODES - 1)], 1);
    }
    __syncthreads();
    int v0 = 0;
    if (t < BNODES) { v0 = cnt[t]; sscan[t] = v0; }
    __syncthreads();
    for (int off = 1; off < BNODES; off <<= 1) {
        int v = 0;
        if (t < BNODES && t >= off) v = sscan[t - off];
        __syncthreads();
        if (t < BNODES) sscan[t] += v;
        __syncthreads();
    }
    if (t < BNODES) {
        const int excl = sscan[t] - v0;
        cur[t] = excl;
        const int node = nodeBase + t;
        if (node < N) {
            offs[node] = regionBase + excl;
            offe[node] = regionBase + excl + v0;
        }
    }
    __syncthreads();
    // counting-sort scatter inside LDS
    for (int k = t; k < count; k += 512) {
        const unsigned v = ldsIn[k];
        const int p = atomicAdd(&cur[v & (BNODES - 1)], 1);
        ldsOut[p] = v >> BSHIFT;
    }
    __syncthreads();
    // sequential coalesced write
    for (int k = t; k < count; k += 512)
        csr_src[regionBase + k] = (int)ldsOut[k];
}

// ---------- layer 1: persistent per-WAVE fused gather + MFMA (DIN=32) ----------
// Each wave strides over 16-row tiles; zero barriers anywhere. LDS rows are
// wave-private; per-wave DS ops are in-order, lgkmcnt(0) syncs write->read.

template <int DIN>
__launch_bounds__(256)
__global__ void fused_l1_kernel(const unsigned short* __restrict__ featb,
                                const unsigned short* __restrict__ whi,
                                const float* __restrict__ bias,
                                const int* __restrict__ csr_src,
                                const int* __restrict__ offs,
                                const int* __restrict__ offe,
                                unsigned short* __restrict__ houtb,
                                int N, int nSteps) {
    constexpr int K   = 2 * DIN;      // 64
    constexpr int STR = K + 8;        // 72
    constexpr int D8  = DIN / 8;      // 4
    __shared__ unsigned short A_s[64 * STR];
    const int tid  = threadIdx.x;
    const int lane = tid & 63;
    const int wave = tid >> 6;
    const int rowBase = wave * 16;            // wave-private A_s rows
    const int lr = lane & 15;
    const int q  = lane >> 4;
    const int nWT = (N + 15) >> 4;            // 16-row tiles
    const int wstride = gridDim.x * 4;

    for (int wt = blockIdx.x * 4 + wave; wt < nWT; wt += wstride) {
        const int nodeBase = wt * 16;

        // self features into k [DIN, 2*DIN)
        for (int i = lane; i < 16 * D8; i += 64) {
            const int row = i / D8, qq = i % D8;
            const int n = min(nodeBase + row, N - 1);
            const uint4 u = *reinterpret_cast<const uint4*>(featb + (size_t)n * DIN + qq * 8);
            *reinterpret_cast<uint4*>(&A_s[(rowBase + row) * STR + DIN + qq * 8]) = u;
        }
        // gather-mean into k [0, DIN): D8 lanes/node, 1 uint4/edge, ONE pass
        {
            const int part = lane % D8;
            const int row  = lane / D8;       // 16 nodes/wave
            const int n = nodeBase + row;
            const uint4* base = reinterpret_cast<const uint4*>(featb);
            unsigned short* dp = &A_s[(rowBase + row) * STR + part * 8];
            if (n < N) {
                const int beg = offs[n];
                const int end = offe[n];
                float a[8] = {0.f, 0.f, 0.f, 0.f, 0.f, 0.f, 0.f, 0.f};
                int k = beg;
                for (; k + 8 <= end; k += 8) {
                    int s[8];
#pragma unroll
                    for (int j = 0; j < 8; ++j) s[j] = csr_src[k + j];
                    uint4 u[8];
#pragma unroll
                    for (int j = 0; j < 8; ++j) u[j] = base[(size_t)s[j] * D8 + part];
#pragma unroll
                    for (int j = 0; j < 8; ++j) acc8(u[j], a);
                }
                for (; k + 4 <= end; k += 4) {
                    const int s0 = csr_src[k + 0];
                    const int s1 = csr_src[k + 1];
                    const int s2 = csr_src[k + 2];
                    const int s3 = csr_src[k + 3];
                    const uint4 u0 = base[(size_t)s0 * D8 + part];
                    const uint4 u1 = base[(size_t)s1 * D8 + part];
                    const uint4 u2 = base[(size_t)s2 * D8 + part];
                    const uint4 u3 = base[(size_t)s3 * D8 + part];
                    acc8(u0, a); acc8(u1, a); acc8(u2, a); acc8(u3, a);
                }
                for (; k < end; ++k) {
                    const uint4 u = base[(size_t)csr_src[k] * D8 + part];
                    acc8(u, a);
                }
                const float inv = 1.0f / fmaxf((float)(end - beg), 1.0f);
                ushort4 lo4, hi4;
                lo4.x = f2bf(a[0] * inv); lo4.y = f2bf(a[1] * inv);
                lo4.z = f2bf(a[2] * inv); lo4.w = f2bf(a[3] * inv);
                hi4.x = f2bf(a[4] * inv); hi4.y = f2bf(a[5] * inv);
                hi4.z = f2bf(a[6] * inv); hi4.w = f2bf(a[7] * inv);
                *reinterpret_cast<ushort4*>(dp)     = lo4;
                *reinterpret_cast<ushort4*>(dp + 4) = hi4;
            } else {
                const ushort4 z = {0, 0, 0, 0};
                *reinterpret_cast<ushort4*>(dp)     = z;
                *reinterpret_cast<ushort4*>(dp + 4) = z;
            }
        }

        // wave-sync (rows wave-private); sched_barrier pins ordering (rule 18)
        asm volatile("s_waitcnt lgkmcnt(0)" ::: "memory");
        __builtin_amdgcn_sched_barrier(0);

        f32x4 acc[4];
#pragma unroll
        for (int t4 = 0; t4 < 4; ++t4) {
            const float b = bias[t4 * 16 + lr];
            acc[t4] = (f32x4){b, b, b, b};
        }
        const unsigned short* Arow = &A_s[(rowBase + lr) * STR + q * 8];
        const unsigned short* Brow = whi + (size_t)lr * K + q * 8;
        for (int s = 0; s < nSteps; ++s) {
            const bf16x8 af = *reinterpret_cast<const bf16x8*>(Arow + s * 32);
#pragma unroll
            for (int t4 = 0; t4 < 4; ++t4) {
                const bf16x8 bh = *reinterpret_cast<const bf16x8*>(
                    Brow + (size_t)t4 * 16 * K + s * 32);
                acc[t4] = __builtin_amdgcn_mfma_f32_16x16x32_bf16(af, bh, acc[t4], 0, 0, 0);
            }
        }
        for (int reg = 0; reg < 4; ++reg) {
            const int n = nodeBase + q * 4 + reg;
            if (n >= N) break;
#pragma unroll
            for (int t4 = 0; t4 < 4; ++t4)
                houtb[(size_t)n * 64 + t4 * 16 + lr] = f2bf(fmaxf(acc[t4][reg], 0.0f));
        }
    }
}

// ---------- layer 2: persistent block-stride fused gather + MFMA + pool ----------
// R31 body inside a tile loop; barriers only around pool zero/flush.

__launch_bounds__(256)
__global__ void fused_l2_pool_kernel(const unsigned short* __restrict__ featb,
                                     const unsigned short* __restrict__ whi,
                                     const float* __restrict__ bias,
                                     const int* __restrict__ csr_src,
                                     const int* __restrict__ offs,
                                     const int* __restrict__ offe,
                                     const int* __restrict__ batch,
                                     float* __restrict__ pool_sum,
                                     int N, int nSteps) {
    constexpr int DIN   = 64;
    constexpr int K     = 2 * DIN;    // 128
    constexpr int STR   = K + 8;      // 136
    constexpr int D8    = DIN / 8;    // 8
    constexpr int NPW   = 64 / D8;    // 8 nodes per wave pass
    constexpr int NPASS = 16 / NPW;   // 2
    __shared__ unsigned short A_s[64 * STR];
    __shared__ float poolLds[16 * 65];
    const int tid  = threadIdx.x;
    const int lane = tid & 63;
    const int wave = tid >> 6;
    const int rowBase = wave * 16;
    const int lr = lane & 15;
    const int q  = lane >> 4;
    const int nTiles = (N + 63) >> 6;

    for (int tile = blockIdx.x; tile < nTiles; tile += gridDim.x) {
        const int nodeBase = tile * 64;

        for (int i = tid; i < 16 * 65; i += 256) poolLds[i] = 0.0f;
        __syncthreads();

        // per-wave: self features into k [DIN, 2*DIN)
        for (int i = lane; i < 16 * D8; i += 64) {
            const int row = i / D8, qq = i % D8;
            const int n = min(nodeBase + rowBase + row, N - 1);
            const uint4 u = *reinterpret_cast<const uint4*>(featb + (size_t)n * DIN + qq * 8);
            *reinterpret_cast<uint4*>(&A_s[(rowBase + row) * STR + DIN + qq * 8]) = u;
        }
        // per-wave gather: D8 lanes/node, 1 uint4/edge, 2 passes
        {
            const int part = lane % D8;
            const uint4* base = reinterpret_cast<const uint4*>(featb);
#pragma unroll
            for (int pass = 0; pass < NPASS; ++pass) {
                const int row = rowBase + pass * NPW + lane / D8;
                const int n = nodeBase + row;
                unsigned short* dp = &A_s[row * STR + part * 8];
                if (n < N) {
                    const int beg = offs[n];
                    const int end = offe[n];
                    float a[8] = {0.f, 0.f, 0.f, 0.f, 0.f, 0.f, 0.f, 0.f};
                    int k = beg;
                    for (; k + 8 <= end; k += 8) {
                        int s[8];
#pragma unroll
                        for (int j = 0; j < 8; ++j) s[j] = csr_src[k + j];
                        uint4 u[8];
#pragma unroll
                        for (int j = 0; j < 8; ++j) u[j] = base[(size_t)s[j] * D8 + part];
#pragma unroll
                        for (int j = 0; j < 8; ++j) acc8(u[j], a);
                    }
                    for (; k + 4 <= end; k += 4) {
                        const int s0 = csr_src[k + 0];
                        const int s1 = csr_src[k + 1];
                        const int s2 = csr_src[k + 2];
                        const int s3 = csr_src[k + 3];
                        const uint4 u0 = base[(size_t)s0 * D8 + part];
                        const uint4 u1 = base[(size_t)s1 * D8 + part];
                        const uint4 u2 = base[(size_t)s2 * D8 + part];
                        const uint4 u3 = base[(size_t)s3 * D8 + part];
                        acc8(u0, a); acc8(u1, a); acc8(u2, a); acc8(u3, a);
                    }
                    for (; k < end; ++k) {
                        const uint4 u = base[(size_t)csr_src[k] * D8 + part];
                        acc8(u, a);
                    }
                    const float inv = 1.0f / fmaxf((float)(end - beg), 1.0f);
                    ushort4 lo4, hi4;
                    lo4.x = f2bf(a[0] * inv); lo4.y = f2bf(a[1] * inv);
                    lo4.z = f2bf(a[2] * inv); lo4.w = f2bf(a[3] * inv);
                    hi4.x = f2bf(a[4] * inv); hi4.y = f2bf(a[5] * inv);
                    hi4.z = f2bf(a[6] * inv); hi4.w = f2bf(a[7] * inv);
                    *reinterpret_cast<ushort4*>(dp)     = lo4;
                    *reinterpret_cast<ushort4*>(dp + 4) = hi4;
                } else {
                    const ushort4 z = {0, 0, 0, 0};
                    *reinterpret_cast<ushort4*>(dp)     = z;
                    *reinterpret_cast<ushort4*>(dp + 4) = z;
                }
            }
        }

        asm volatile("s_waitcnt lgkmcnt(0)" ::: "memory");
        __builtin_amdgcn_sched_barrier(0);

        f32x4 acc[4];
#pragma unroll
        for (int t4 = 0; t4 < 4; ++t4) {
            const float b = bias[t4 * 16 + lr];
            acc[t4] = (f32x4){b, b, b, b};
        }
        const unsigned short* Arow = &A_s[(rowBase + lr) * STR + q * 8];
        const unsigned short* Brow = whi + (size_t)lr * K + q * 8;
        for (int s = 0; s < nSteps; ++s) {
            const bf16x8 af = *reinterpret_cast<const bf16x8*>(Arow + s * 32);
#pragma unroll
            for (int t4 = 0; t4 < 4; ++t4) {
                const bf16x8 bh = *reinterpret_cast<const bf16x8*>(
                    Brow + (size_t)t4 * 16 * K + s * 32);
                acc[t4] = __builtin_amdgcn_mfma_f32_16x16x32_bf16(af, bh, acc[t4], 0, 0, 0);
            }
        }

        // pool epilogue (R29/R31): LDS accumulate + boundary-only atomics
        {
            const int g0 = batch[nodeBase];
            float ag[4] = {0.f, 0.f, 0.f, 0.f};
            int gcur = -1;
            auto flush_run = [&](int g) {
                const int r = g - g0;
                if (r < 16) {
#pragma unroll
                    for (int t4 = 0; t4 < 4; ++t4)
                        atomicAdd(&poolLds[r * 65 + t4 * 16 + lr], ag[t4]);
                } else {   // statistically never (graphs avg ~50 nodes)
#pragma unroll
                    for (int t4 = 0; t4 < 4; ++t4)
                        atomicAdd(&pool_sum[(size_t)g * 64 + t4 * 16 + lr], ag[t4]);
                }
            };
            for (int reg = 0; reg < 4; ++reg) {
                const int n = nodeBase + rowBase + q * 4 + reg;
                if (n >= N) break;
                const int g = batch[n];          // sorted
                if (g != gcur) {
                    if (gcur >= 0) flush_run(gcur);
                    gcur = g;
                    ag[0] = ag[1] = ag[2] = ag[3] = 0.f;
                }
#pragma unroll
                for (int t4 = 0; t4 < 4; ++t4)
                    ag[t4] += fmaxf(acc[t4][reg], 0.0f);
            }
            if (gcur >= 0) flush_run(gcur);
            __syncthreads();
            // interior rows sole-writer -> plain store; boundary -> atomicAdd
            const int glast = batch[min(nodeBase + 63, N - 1)];
            const int S = min(glast - g0 + 1, 16);
            for (int i = tid; i < S * 64; i += 256) {
                const int r = i >> 6, c = i & 63;
                const float v = poolLds[r * 65 + c];
                float* dstp = &pool_sum[(size_t)(g0 + r) * 64 + c];
                if (r == 0 || r == S - 1) atomicAdd(dstp, v);
                else *dstp = v;
            }
            __syncthreads();   // flush reads done before next tile's zero
        }
    }
}

// ---------- head: per-graph count via binary search over sorted batch ----------

__device__ inline int lower_bound_batch(const int* __restrict__ batch, int N, int key) {
    int lo = 0, hi = N;
    while (lo < hi) {
        const int mid = (lo + hi) >> 1;
        if (batch[mid] < key) lo = mid + 1; else hi = mid;
    }
    return lo;
}

__global__ void final_kernel(const float* __restrict__ pool_sum,
                             const int* __restrict__ batch,
                             const float* __restrict__ W_lin,
                             const float* __restrict__ b_lin,
                             float* __restrict__ out, int G, int N) {
    int t = blockIdx.x * blockDim.x + threadIdx.x;
    if (t >= G * 2) return;
    int g = t >> 1, o = t & 1;
    const int c0 = lower_bound_batch(batch, N, g);
    const int c1 = lower_bound_batch(batch, N, g + 1);
    float inv = 1.0f / fmaxf((float)(c1 - c0), 1.0f);
    float acc = b_lin[o];
#pragma unroll
    for (int c = 0; c < 64; ++c)
        acc = fmaf(pool_sum[(size_t)g * 64 + c] * inv, W_lin[o * 64 + c], acc);
    out[t] = acc;
}

extern "C" void kernel_launch(void* const* d_in, const int* in_sizes, int n_in,
                              void* d_out, int out_size, void* d_ws, size_t ws_size,
                              hipStream_t stream) {
    const float* x     = (const float*)d_in[0];
    const int*   ei    = (const int*)d_in[1];
    const int*   batch = (const int*)d_in[2];
    const float* W1_l  = (const float*)d_in[3];
    const float* b1    = (const float*)d_in[4];
    const float* W1_r  = (const float*)d_in[5];
    const float* W2_l  = (const float*)d_in[6];
    const float* b2    = (const float*)d_in[7];
    const float* W2_r  = (const float*)d_in[8];
    const float* W_lin = (const float*)d_in[9];
    const float* b_lin = (const float*)d_in[10];

    const int N = in_sizes[0] / 32;
    const int E = in_sizes[1] / 2;
    const int G = out_size / 2;
    const int* src = ei;
    const int* dst = ei + E;
    const int NB = (N + BNODES - 1) >> BSHIFT;   // 782 for N=200000

    char* p = (char*)d_ws;
    auto carve = [&](size_t bytes) -> void* {
        void* r = (void*)p;
        p += (bytes + (WS_ALIGN - 1)) / WS_ALIGN * WS_ALIGN;
        return r;
    };
    int*            bucketCursor = (int*)carve((size_t)MAXNB * 4);
    unsigned*       bucketData   = (unsigned*)carve((size_t)NB * BCAP * 4);
    int*            offs         = (int*)carve((size_t)N * 4);
    int*            offe         = (int*)carve((size_t)N * 4);
    int*            csr_src      = (int*)carve((size_t)NB * BCAP * 4);
    unsigned short* xb           = (unsigned short*)carve((size_t)N * 32 * 2);
    unsigned short* h1b          = (unsigned short*)carve((size_t)N * 64 * 2);
    unsigned short* whi1         = (unsigned short*)carve(64 * 64 * 2);
    unsigned short* whi2         = (unsigned short*)carve(64 * 128 * 2);
    float*          pool         = (float*)carve((size_t)G * 64 * 4);
    float*          out          = (float*)d_out;

    const int TB = 256;
    const int total4 = N * 32 / 4;
    prep_kernel<<<(total4 + TB - 1) / TB, TB, 0, stream>>>(
        x, xb, W1_l, W1_r, W2_l, W2_r, whi1, whi2, bucketCursor, pool,
        N, NB, G, total4);
    bucket_scatter_kernel<<<(E + EPB - 1) / EPB, 512, 0, stream>>>(src, dst, bucketCursor,
                                                                   bucketData, E, NB);
    csr_build_kernel<<<NB, 512, 0, stream>>>(bucketData, bucketCursor, offs, offe, csr_src, N);

    // layer 1: persistent per-wave fused gather + MFMA 32->64 + relu -> h1b
    const int nWT = (N + 15) >> 4;
    const int grid1 = min(2048, (nWT + 3) / 4);
    fused_l1_kernel<32><<<grid1, TB, 0, stream>>>(
        xb, whi1, b1, csr_src, offs, offe, h1b, N, 2);

    // layer 2: persistent block-stride fused gather + MFMA 64->64 + relu + pool
    const int nTiles = (N + 63) >> 6;
    const int grid2 = min(1792, nTiles);
    fused_l2_pool_kernel<<<grid2, TB, 0, stream>>>(
        h1b, whi2, b2, csr_src, offs, offe, batch, pool, N, 4);

    final_kernel<<<(G * 2 + TB - 1) / TB, TB, 0, stream>>>(pool, batch, W_lin, b_lin,
                                                           out, G, N);
}

// Round 14
// 308.760 us; speedup vs baseline: 1.1440x; 1.0479x over previous
//
#include <hip/hip_runtime.h>
#include <hip/hip_bf16.h>

// JetGNN: 2-layer SAGEConv(mean) + ReLU + global_mean_pool + Linear(64->2)
// R1-R21: scan/CSR/pool/agg/MFMA ladder. 355.7us R21.
// R22-R32: fusion arc. fused2 floor ~96us robust across 5 structures.
// R29: LDS pool. R31: wave-autonomous. R33: LDS counting-sort prep, 324.7.
// R34: persistent tiles both layers + 512-thr prep. total 323.6 BUT
//      decomposes: fused2 persistent REGRESSED 96.5->113.2 (intra-block
//      tile serialization kills backfill; VGPR 56->68, occ 37->28.7);
//      fused1-persistent + 512-thr prep WON ~18us.
// R35: recombine measured-best: fused2 = R33 non-persistent wave-autonomous
//      (96.5us, twice-measured); fused1 persistent per-wave (R34); 512-thr
//      scatter/csr (R34). No new mechanism.

#define WS_ALIGN 64
#define EPB 4096          // edges per block in bucket_scatter (512 thr x 8)
#define BSHIFT 8          // 256 nodes per bucket
#define BNODES 256
#define BCAP 6144         // region capacity (mean 4096, sd 64, +32 sigma)
#define MAXNB 1024

typedef short bf16x8 __attribute__((ext_vector_type(8)));
typedef float f32x4 __attribute__((ext_vector_type(4)));

__device__ inline unsigned short f2bf(float f) {   // RNE f32->bf16 (finite inputs)
    unsigned u = __float_as_uint(f);
    return (unsigned short)((u + 0x7fffu + ((u >> 16) & 1u)) >> 16);
}

__device__ inline void acc8(const uint4 u, float* a) {  // 8 bf16 -> fp32 accumulate
    a[0] += __uint_as_float(u.x << 16);
    a[1] += __uint_as_float(u.x & 0xffff0000u);
    a[2] += __uint_as_float(u.y << 16);
    a[3] += __uint_as_float(u.y & 0xffff0000u);
    a[4] += __uint_as_float(u.z << 16);
    a[5] += __uint_as_float(u.z & 0xffff0000u);
    a[6] += __uint_as_float(u.w << 16);
    a[7] += __uint_as_float(u.w & 0xffff0000u);
}

// ---------- prep: x->bf16 cvt + weight prepack + cursors + pool zero ----------

__global__ void prep_kernel(const float* __restrict__ x, unsigned short* __restrict__ xb,
                            const float* __restrict__ W1_l, const float* __restrict__ W1_r,
                            const float* __restrict__ W2_l, const float* __restrict__ W2_r,
                            unsigned short* __restrict__ whi1, unsigned short* __restrict__ whi2,
                            int* __restrict__ bucketCursor, float* __restrict__ pool,
                            int N, int NB, int G, int total4) {
    const int gid = blockIdx.x * blockDim.x + threadIdx.x;
    if (gid < total4) {
        const float4 v = reinterpret_cast<const float4*>(x)[gid];
        ushort4 o;
        o.x = f2bf(v.x); o.y = f2bf(v.y); o.z = f2bf(v.z); o.w = f2bf(v.w);
        reinterpret_cast<ushort4*>(xb)[gid] = o;
    }
    if (gid < NB) bucketCursor[gid] = gid * BCAP;
    if (gid < G * 64) pool[gid] = 0.0f;     // consumed only by fused2 (later launch)
    if (gid < 64 * 64) {        // whi1: rows [o][k], K=64
        const int o = gid >> 6, k = gid & 63;
        const float v = (k < 32) ? W1_l[o * 32 + k] : W1_r[o * 32 + (k - 32)];
        whi1[gid] = f2bf(v);
    }
    if (gid < 64 * 128) {       // whi2: rows [o][k], K=128
        const int o = gid >> 7, k = gid & 127;
        const float v = (k < 64) ? W2_l[o * 64 + k] : W2_r[o * 64 + (k - 64)];
        whi2[gid] = f2bf(v);
    }
}

// ---------- bucket scatter: 512-thr LDS counting-sort, coalesced writeout ----

__global__ __launch_bounds__(512) void bucket_scatter_kernel(const int* __restrict__ src,
                                                             const int* __restrict__ dst,
                                                             int* __restrict__ bucketCursor,
                                                             unsigned* __restrict__ bucketData,
                                                             int E, int NB) {
    __shared__ int hist[MAXNB];
    __shared__ int lofs[MAXNB];
    __shared__ int lcur[MAXNB];
    __shared__ int gbase[MAXNB];
    __shared__ int sscan[512];
    __shared__ unsigned staged[EPB];   // records sorted by bucket
    __shared__ int gaddr[EPB];         // precomputed global position (-1 = drop)
    const int t = threadIdx.x;
    for (int i = t; i < MAXNB; i += 512) hist[i] = 0;
    __syncthreads();
    const int eBase = blockIdx.x * EPB + t;
    int bkt[8]; unsigned rec[8];
#pragma unroll
    for (int j = 0; j < 8; ++j) {
        const int e = eBase + j * 512;
        if (e < E) {
            const int d = dst[e];
            bkt[j] = d >> BSHIFT;
            rec[j] = ((unsigned)src[e] << BSHIFT) | (unsigned)(d & (BNODES - 1));
            atomicAdd(&hist[bkt[j]], 1);
        } else {
            bkt[j] = -1;
        }
    }
    __syncthreads();
    // exclusive scan of hist[0..1024) with 512 threads (2 entries each)
    const int b2 = t * 2;
    const int h0 = hist[b2], h1 = hist[b2 + 1];
    const int tsum = h0 + h1;
    sscan[t] = tsum;
    __syncthreads();
    for (int off = 1; off < 512; off <<= 1) {
        const int v = (t >= off) ? sscan[t - off] : 0;
        __syncthreads();
        sscan[t] += v;
        __syncthreads();
    }
    const int excl = sscan[t] - tsum;
    lofs[b2]     = excl;
    lofs[b2 + 1] = excl + h0;
    lcur[b2]     = excl;
    lcur[b2 + 1] = excl + h0;
    // reserve global runs (one atomic per non-empty bucket per block)
    for (int bb = t; bb < NB; bb += 512)
        if (hist[bb] > 0) gbase[bb] = atomicAdd(&bucketCursor[bb], hist[bb]);
    __syncthreads();
    // place into bucket-sorted LDS order, precompute global addresses
#pragma unroll
    for (int j = 0; j < 8; ++j) {
        if (bkt[j] >= 0) {
            const int b = bkt[j];
            const int lp = atomicAdd(&lcur[b], 1);
            staged[lp] = rec[j];
            const int gp = gbase[b] + (lp - lofs[b]);
            gaddr[lp] = (gp < (b + 1) * BCAP) ? gp : -1;  // overflow guard
        }
    }
    __syncthreads();
    // writeout in sorted order: consecutive i -> consecutive addrs within runs
    const int cnt = min(EPB, E - blockIdx.x * EPB);
    for (int i = t; i < cnt; i += 512) {
        const int p = gaddr[i];
        if (p >= 0) bucketData[p] = staged[i];
    }
}

// 512-thr, one block per bucket: region staged in LDS, counting-sort by
// dstLocal in LDS, csr_src written as one sequential coalesced stream.
__global__ __launch_bounds__(512) void csr_build_kernel(const unsigned* __restrict__ bucketData,
                                                        const int* __restrict__ bucketCursor,
                                                        int* __restrict__ offs,
                                                        int* __restrict__ offe,
                                                        int* __restrict__ csr_src,
                                                        int N) {
    __shared__ unsigned ldsIn[BCAP];    // 24KB
    __shared__ unsigned ldsOut[BCAP];   // 24KB
    __shared__ int cnt[BNODES];
    __shared__ int sscan[BNODES];
    __shared__ int cur[BNODES];
    const int t   = threadIdx.x;
    const int bkt = blockIdx.x;
    const int nodeBase = bkt << BSHIFT;
    const int regionBase = bkt * BCAP;
    const int count = min(bucketCursor[bkt] - regionBase, BCAP);
    if (t < BNODES) cnt[t] = 0;
    __syncthreads();
    // stage region (coalesced read) + histogram from LDS
    for (int k = t; k < count; k += 512) {
        const unsigned v = bucketData[regionBase + k];
        ldsIn[k] = v;
        atomicAdd(&cnt[v & (BNODES - 1)], 1);
    }
    __syncthreads();
    int v0 = 0;
    if (t < BNODES) { v0 = cnt[t]; sscan[t] = v0; }
    __syncthreads();
    for (int off = 1; off < BNODES; off <<= 1) {
        int v = 0;
        if (t < BNODES && t >= off) v = sscan[t - off];
        __syncthreads();
        if (t < BNODES) sscan[t] += v;
        __syncthreads();
    }
    if (t < BNODES) {
        const int excl = sscan[t] - v0;
        cur[t] = excl;
        const int node = nodeBase + t;
        if (node < N) {
            offs[node] = regionBase + excl;
            offe[node] = regionBase + excl + v0;
        }
    }
    __syncthreads();
    // counting-sort scatter inside LDS
    for (int k = t; k < count; k += 512) {
        const unsigned v = ldsIn[k];
        const int p = atomicAdd(&cur[v & (BNODES - 1)], 1);
        ldsOut[p] = v >> BSHIFT;
    }
    __syncthreads();
    // sequential coalesced write
    for (int k = t; k < count; k += 512)
        csr_src[regionBase + k] = (int)ldsOut[k];
}

// ---------- layer 1: persistent per-WAVE fused gather + MFMA (DIN=32) ----------
// Each wave strides over 16-row tiles; zero barriers anywhere. LDS rows are
// wave-private; per-wave DS ops are in-order, lgkmcnt(0) syncs write->read.

template <int DIN>
__launch_bounds__(256)
__global__ void fused_l1_kernel(const unsigned short* __restrict__ featb,
                                const unsigned short* __restrict__ whi,
                                const float* __restrict__ bias,
                                const int* __restrict__ csr_src,
                                const int* __restrict__ offs,
                                const int* __restrict__ offe,
                                unsigned short* __restrict__ houtb,
                                int N, int nSteps) {
    constexpr int K   = 2 * DIN;      // 64
    constexpr int STR = K + 8;        // 72
    constexpr int D8  = DIN / 8;      // 4
    __shared__ unsigned short A_s[64 * STR];
    const int tid  = threadIdx.x;
    const int lane = tid & 63;
    const int wave = tid >> 6;
    const int rowBase = wave * 16;            // wave-private A_s rows
    const int lr = lane & 15;
    const int q  = lane >> 4;
    const int nWT = (N + 15) >> 4;            // 16-row tiles
    const int wstride = gridDim.x * 4;

    for (int wt = blockIdx.x * 4 + wave; wt < nWT; wt += wstride) {
        const int nodeBase = wt * 16;

        // self features into k [DIN, 2*DIN)
        for (int i = lane; i < 16 * D8; i += 64) {
            const int row = i / D8, qq = i % D8;
            const int n = min(nodeBase + row, N - 1);
            const uint4 u = *reinterpret_cast<const uint4*>(featb + (size_t)n * DIN + qq * 8);
            *reinterpret_cast<uint4*>(&A_s[(rowBase + row) * STR + DIN + qq * 8]) = u;
        }
        // gather-mean into k [0, DIN): D8 lanes/node, 1 uint4/edge, ONE pass
        {
            const int part = lane % D8;
            const int row  = lane / D8;       // 16 nodes/wave
            const int n = nodeBase + row;
            const uint4* base = reinterpret_cast<const uint4*>(featb);
            unsigned short* dp = &A_s[(rowBase + row) * STR + part * 8];
            if (n < N) {
                const int beg = offs[n];
                const int end = offe[n];
                float a[8] = {0.f, 0.f, 0.f, 0.f, 0.f, 0.f, 0.f, 0.f};
                int k = beg;
                for (; k + 8 <= end; k += 8) {
                    int s[8];
#pragma unroll
                    for (int j = 0; j < 8; ++j) s[j] = csr_src[k + j];
                    uint4 u[8];
#pragma unroll
                    for (int j = 0; j < 8; ++j) u[j] = base[(size_t)s[j] * D8 + part];
#pragma unroll
                    for (int j = 0; j < 8; ++j) acc8(u[j], a);
                }
                for (; k + 4 <= end; k += 4) {
                    const int s0 = csr_src[k + 0];
                    const int s1 = csr_src[k + 1];
                    const int s2 = csr_src[k + 2];
                    const int s3 = csr_src[k + 3];
                    const uint4 u0 = base[(size_t)s0 * D8 + part];
                    const uint4 u1 = base[(size_t)s1 * D8 + part];
                    const uint4 u2 = base[(size_t)s2 * D8 + part];
                    const uint4 u3 = base[(size_t)s3 * D8 + part];
                    acc8(u0, a); acc8(u1, a); acc8(u2, a); acc8(u3, a);
                }
                for (; k < end; ++k) {
                    const uint4 u = base[(size_t)csr_src[k] * D8 + part];
                    acc8(u, a);
                }
                const float inv = 1.0f / fmaxf((float)(end - beg), 1.0f);
                ushort4 lo4, hi4;
                lo4.x = f2bf(a[0] * inv); lo4.y = f2bf(a[1] * inv);
                lo4.z = f2bf(a[2] * inv); lo4.w = f2bf(a[3] * inv);
                hi4.x = f2bf(a[4] * inv); hi4.y = f2bf(a[5] * inv);
                hi4.z = f2bf(a[6] * inv); hi4.w = f2bf(a[7] * inv);
                *reinterpret_cast<ushort4*>(dp)     = lo4;
                *reinterpret_cast<ushort4*>(dp + 4) = hi4;
            } else {
                const ushort4 z = {0, 0, 0, 0};
                *reinterpret_cast<ushort4*>(dp)     = z;
                *reinterpret_cast<ushort4*>(dp + 4) = z;
            }
        }

        // wave-sync (rows wave-private); sched_barrier pins ordering (rule 18)
        asm volatile("s_waitcnt lgkmcnt(0)" ::: "memory");
        __builtin_amdgcn_sched_barrier(0);

        f32x4 acc[4];
#pragma unroll
        for (int t4 = 0; t4 < 4; ++t4) {
            const float b = bias[t4 * 16 + lr];
            acc[t4] = (f32x4){b, b, b, b};
        }
        const unsigned short* Arow = &A_s[(rowBase + lr) * STR + q * 8];
        const unsigned short* Brow = whi + (size_t)lr * K + q * 8;
        for (int s = 0; s < nSteps; ++s) {
            const bf16x8 af = *reinterpret_cast<const bf16x8*>(Arow + s * 32);
#pragma unroll
            for (int t4 = 0; t4 < 4; ++t4) {
                const bf16x8 bh = *reinterpret_cast<const bf16x8*>(
                    Brow + (size_t)t4 * 16 * K + s * 32);
                acc[t4] = __builtin_amdgcn_mfma_f32_16x16x32_bf16(af, bh, acc[t4], 0, 0, 0);
            }
        }
        for (int reg = 0; reg < 4; ++reg) {
            const int n = nodeBase + q * 4 + reg;
            if (n >= N) break;
#pragma unroll
            for (int t4 = 0; t4 < 4; ++t4)
                houtb[(size_t)n * 64 + t4 * 16 + lr] = f2bf(fmaxf(acc[t4][reg], 0.0f));
        }
    }
}

// ---------- layer 2: wave-autonomous fused gather + MFMA + pool (R33 exact) ----
// Non-persistent: one 64-node tile per block; grid backfill overlaps tails.

template <int DIN, bool POOL>
__launch_bounds__(256)
__global__ void fused_agg_mfma_kernel(const unsigned short* __restrict__ featb,
                                      const unsigned short* __restrict__ whi,
                                      const float* __restrict__ bias,
                                      const int* __restrict__ csr_src,
                                      const int* __restrict__ offs,
                                      const int* __restrict__ offe,
                                      unsigned short* __restrict__ houtb,
                                      const int* __restrict__ batch,
                                      float* __restrict__ pool_sum,
                                      int N, int nSteps) {
    constexpr int K     = 2 * DIN;    // 128
    constexpr int STR   = K + 8;      // 136 ushorts, rows 16B-aligned
    constexpr int D8    = DIN / 8;    // 8
    constexpr int NPW   = 64 / D8;    // 8 nodes per wave pass
    constexpr int NPASS = 16 / NPW;   // 2
    __shared__ unsigned short A_s[64 * STR];
    __shared__ float poolLds[POOL ? 16 * 65 : 1];   // [graph-row][ch]
    const int tid  = threadIdx.x;
    const int lane = tid & 63;
    const int wave = tid >> 6;
    const int nodeBase = blockIdx.x * 64;
    const int rowBase  = wave * 16;           // wave-owned A_s rows

    if (POOL) {
        for (int i = tid; i < 16 * 65; i += 256) poolLds[i] = 0.0f;
        __syncthreads();   // cheap: pre-gather, all waves arrive together
    }

    // ---- per-wave: self features into k [DIN, 2*DIN) of rows [rowBase,+16) ----
    for (int i = lane; i < 16 * D8; i += 64) {
        const int row = rowBase + i / D8, q = i % D8;
        const int n = min(nodeBase + row, N - 1);
        const uint4 u = *reinterpret_cast<const uint4*>(featb + (size_t)n * DIN + q * 8);
        *reinterpret_cast<uint4*>(&A_s[row * STR + DIN + q * 8]) = u;
    }

    // ---- per-wave: gather-mean into k [0, DIN): D8 lanes/node, 1 uint4/edge ----
    {
        const int part = lane % D8;
        const uint4* base = reinterpret_cast<const uint4*>(featb);
#pragma unroll
        for (int pass = 0; pass < NPASS; ++pass) {
            const int row = rowBase + pass * NPW + lane / D8;
            const int n = nodeBase + row;
            unsigned short* dp = &A_s[row * STR + part * 8];
            if (n < N) {
                const int beg = offs[n];
                const int end = offe[n];
                float a[8] = {0.f, 0.f, 0.f, 0.f, 0.f, 0.f, 0.f, 0.f};
                int k = beg;
                for (; k + 8 <= end; k += 8) {       // 8 uint4 in flight
                    int s[8];
#pragma unroll
                    for (int j = 0; j < 8; ++j) s[j] = csr_src[k + j];
                    uint4 u[8];
#pragma unroll
                    for (int j = 0; j < 8; ++j) u[j] = base[(size_t)s[j] * D8 + part];
#pragma unroll
                    for (int j = 0; j < 8; ++j) acc8(u[j], a);
                }
                for (; k + 4 <= end; k += 4) {
                    const int s0 = csr_src[k + 0];
                    const int s1 = csr_src[k + 1];
                    const int s2 = csr_src[k + 2];
                    const int s3 = csr_src[k + 3];
                    const uint4 u0 = base[(size_t)s0 * D8 + part];
                    const uint4 u1 = base[(size_t)s1 * D8 + part];
                    const uint4 u2 = base[(size_t)s2 * D8 + part];
                    const uint4 u3 = base[(size_t)s3 * D8 + part];
                    acc8(u0, a); acc8(u1, a); acc8(u2, a); acc8(u3, a);
                }
                for (; k < end; ++k) {
                    const uint4 u = base[(size_t)csr_src[k] * D8 + part];
                    acc8(u, a);
                }
                const float inv = 1.0f / fmaxf((float)(end - beg), 1.0f);
                ushort4 lo4, hi4;
                lo4.x = f2bf(a[0] * inv); lo4.y = f2bf(a[1] * inv);
                lo4.z = f2bf(a[2] * inv); lo4.w = f2bf(a[3] * inv);
                hi4.x = f2bf(a[4] * inv); hi4.y = f2bf(a[5] * inv);
                hi4.z = f2bf(a[6] * inv); hi4.w = f2bf(a[7] * inv);
                *reinterpret_cast<ushort4*>(dp)     = lo4;
                *reinterpret_cast<ushort4*>(dp + 4) = hi4;
            } else {
                const ushort4 z = {0, 0, 0, 0};
                *reinterpret_cast<ushort4*>(dp)     = z;
                *reinterpret_cast<ushort4*>(dp + 4) = z;
            }
        }
    }

    // wave-sync: drain this wave's LDS writes before its ds_reads (no block
    // barrier -- rows are wave-private). sched_barrier pins ordering (rule 18).
    asm volatile("s_waitcnt lgkmcnt(0)" ::: "memory");
    __builtin_amdgcn_sched_barrier(0);

    const int lr = lane & 15;        // A: m (node); B: n (out); D: col (out)
    const int q  = lane >> 4;        // frag k-quad; D row group
    f32x4 acc[4];
#pragma unroll
    for (int t = 0; t < 4; ++t) {
        const float b = bias[t * 16 + lr];
        acc[t] = (f32x4){b, b, b, b};
    }
    const unsigned short* Arow = &A_s[(rowBase + lr) * STR + q * 8];
    const unsigned short* Brow = whi + (size_t)lr * K + q * 8;   // + t*16*K + s*32
    for (int s = 0; s < nSteps; ++s) {    // runtime: no full unroll (R11)
        const bf16x8 af = *reinterpret_cast<const bf16x8*>(Arow + s * 32);
#pragma unroll
        for (int t = 0; t < 4; ++t) {
            const bf16x8 bh = *reinterpret_cast<const bf16x8*>(
                Brow + (size_t)t * 16 * K + s * 32);
            acc[t] = __builtin_amdgcn_mfma_f32_16x16x32_bf16(af, bh, acc[t], 0, 0, 0);
        }
    }

    // D layout: row(node local 16) = q*4 + reg, col(out) = t*16 + lr
    if (POOL) {
        const int g0 = batch[nodeBase];
        float ag[4] = {0.f, 0.f, 0.f, 0.f};
        int gcur = -1;
        auto flush_run = [&](int g) {
            const int r = g - g0;
            if (r < 16) {
#pragma unroll
                for (int t = 0; t < 4; ++t)
                    atomicAdd(&poolLds[r * 65 + t * 16 + lr], ag[t]);
            } else {       // statistically never (graphs avg ~50 nodes)
#pragma unroll
                for (int t = 0; t < 4; ++t)
                    atomicAdd(&pool_sum[(size_t)g * 64 + t * 16 + lr], ag[t]);
            }
        };
        for (int reg = 0; reg < 4; ++reg) {
            const int n = nodeBase + rowBase + q * 4 + reg;
            if (n >= N) break;
            const int g = batch[n];              // sorted
            if (g != gcur) {
                if (gcur >= 0) flush_run(gcur);
                gcur = g;
                ag[0] = ag[1] = ag[2] = ag[3] = 0.f;
            }
#pragma unroll
            for (int t = 0; t < 4; ++t)
                ag[t] += fmaxf(acc[t][reg], 0.0f);
        }
        if (gcur >= 0) flush_run(gcur);
        __syncthreads();
        // flush: interior rows sole-writer -> plain store (pool pre-zeroed);
        // boundary rows (r==0, r==S-1) -> global atomicAdd.
        const int glast = batch[min(nodeBase + 63, N - 1)];
        const int S = min(glast - g0 + 1, 16);
        for (int i = tid; i < S * 64; i += 256) {
            const int r = i >> 6, c = i & 63;
            const float v = poolLds[r * 65 + c];
            float* dstp = &pool_sum[(size_t)(g0 + r) * 64 + c];
            if (r == 0 || r == S - 1) atomicAdd(dstp, v);
            else *dstp = v;
        }
    } else {
        for (int reg = 0; reg < 4; ++reg) {
            const int n = nodeBase + rowBase + q * 4 + reg;
            if (n >= N) break;
#pragma unroll
            for (int t = 0; t < 4; ++t)
                houtb[(size_t)n * 64 + t * 16 + lr] = f2bf(fmaxf(acc[t][reg], 0.0f));
        }
    }
}

// ---------- head: per-graph count via binary search over sorted batch ----------

__device__ inline int lower_bound_batch(const int* __restrict__ batch, int N, int key) {
    int lo = 0, hi = N;
    while (lo < hi) {
        const int mid = (lo + hi) >> 1;
        if (batch[mid] < key) lo = mid + 1; else hi = mid;
    }
    return lo;
}

__global__ void final_kernel(const float* __restrict__ pool_sum,
                             const int* __restrict__ batch,
                             const float* __restrict__ W_lin,
                             const float* __restrict__ b_lin,
                             float* __restrict__ out, int G, int N) {
    int t = blockIdx.x * blockDim.x + threadIdx.x;
    if (t >= G * 2) return;
    int g = t >> 1, o = t & 1;
    const int c0 = lower_bound_batch(batch, N, g);
    const int c1 = lower_bound_batch(batch, N, g + 1);
    float inv = 1.0f / fmaxf((float)(c1 - c0), 1.0f);
    float acc = b_lin[o];
#pragma unroll
    for (int c = 0; c < 64; ++c)
        acc = fmaf(pool_sum[(size_t)g * 64 + c] * inv, W_lin[o * 64 + c], acc);
    out[t] = acc;
}

extern "C" void kernel_launch(void* const* d_in, const int* in_sizes, int n_in,
                              void* d_out, int out_size, void* d_ws, size_t ws_size,
                              hipStream_t stream) {
    const float* x     = (const float*)d_in[0];
    const int*   ei    = (const int*)d_in[1];
    const int*   batch = (const int*)d_in[2];
    const float* W1_l  = (const float*)d_in[3];
    const float* b1    = (const float*)d_in[4];
    const float* W1_r  = (const float*)d_in[5];
    const float* W2_l  = (const float*)d_in[6];
    const float* b2    = (const float*)d_in[7];
    const float* W2_r  = (const float*)d_in[8];
    const float* W_lin = (const float*)d_in[9];
    const float* b_lin = (const float*)d_in[10];

    const int N = in_sizes[0] / 32;
    const int E = in_sizes[1] / 2;
    const int G = out_size / 2;
    const int* src = ei;
    const int* dst = ei + E;
    const int NB = (N + BNODES - 1) >> BSHIFT;   // 782 for N=200000

    char* p = (char*)d_ws;
    auto carve = [&](size_t bytes) -> void* {
        void* r = (void*)p;
        p += (bytes + (WS_ALIGN - 1)) / WS_ALIGN * WS_ALIGN;
        return r;
    };
    int*            bucketCursor = (int*)carve((size_t)MAXNB * 4);
    unsigned*       bucketData   = (unsigned*)carve((size_t)NB * BCAP * 4);
    int*            offs         = (int*)carve((size_t)N * 4);
    int*            offe         = (int*)carve((size_t)N * 4);
    int*            csr_src      = (int*)carve((size_t)NB * BCAP * 4);
    unsigned short* xb           = (unsigned short*)carve((size_t)N * 32 * 2);
    unsigned short* h1b          = (unsigned short*)carve((size_t)N * 64 * 2);
    unsigned short* whi1         = (unsigned short*)carve(64 * 64 * 2);
    unsigned short* whi2         = (unsigned short*)carve(64 * 128 * 2);
    float*          pool         = (float*)carve((size_t)G * 64 * 4);
    float*          out          = (float*)d_out;

    const int TB = 256;
    const int total4 = N * 32 / 4;
    prep_kernel<<<(total4 + TB - 1) / TB, TB, 0, stream>>>(
        x, xb, W1_l, W1_r, W2_l, W2_r, whi1, whi2, bucketCursor, pool,
        N, NB, G, total4);
    bucket_scatter_kernel<<<(E + EPB - 1) / EPB, 512, 0, stream>>>(src, dst, bucketCursor,
                                                                   bucketData, E, NB);
    csr_build_kernel<<<NB, 512, 0, stream>>>(bucketData, bucketCursor, offs, offe, csr_src, N);

    // layer 1: persistent per-wave fused gather + MFMA 32->64 + relu -> h1b
    const int nWT = (N + 15) >> 4;
    const int grid1 = min(2048, (nWT + 3) / 4);
    fused_l1_kernel<32><<<grid1, TB, 0, stream>>>(
        xb, whi1, b1, csr_src, offs, offe, h1b, N, 2);

    // layer 2: non-persistent wave-autonomous fused gather + MFMA + pool (R33)
    fused_agg_mfma_kernel<64, true><<<(N + 63) / 64, TB, 0, stream>>>(
        h1b, whi2, b2, csr_src, offs, offe, nullptr, batch, pool, N, 4);

    final_kernel<<<(G * 2 + TB - 1) / TB, TB, 0, stream>>>(pool, batch, W_lin, b_lin,
                                                           out, G, N);
}

// Round 17
// 304.308 us; speedup vs baseline: 1.1608x; 1.0146x over previous
//
#include <hip/hip_runtime.h>
#include <hip/hip_bf16.h>

// JetGNN: 2-layer SAGEConv(mean) + ReLU + global_mean_pool + Linear(64->2)
// R1-R21: scan/CSR/pool/agg/MFMA ladder. 355.7us R21.
// R22-R32: fusion arc; fused2 floor ~96us robust across 6 structures.
// R29: LDS pool. R31: wave-autonomous. R33: LDS counting-sort prep.
// R34/R35: persistent fused1 + 512-thr prep + non-persistent fused2 = 308.8.
// R36: (1) prep kernel deleted: cursors made RELATIVE (zero-init via
//      hipMemsetAsync), pool zeroed via hipMemsetAsync, xb/whi conversion
//      grid-strided INSIDE bucket_scatter before its scatter phase.
//      (2) BCAP 6144->4608 (+8 sigma still): csr_build LDS 51->39KB ->
//      4 blocks/CU -> 782 blocks fit ONE round (was 1.02 rounds = full
//      second-round tail). Smaller bucketData also helps write locality.
// R37/R38: identical resubmits (R36/R37 benches hit GPUAcquisitionTimeout).

#define WS_ALIGN 64
#define EPB 4096          // edges per block in bucket_scatter (512 thr x 8)
#define BSHIFT 8          // 256 nodes per bucket
#define BNODES 256
#define BCAP 4608         // region capacity (mean 4096, sd 64, +8 sigma)
#define MAXNB 1024

typedef short bf16x8 __attribute__((ext_vector_type(8)));
typedef float f32x4 __attribute__((ext_vector_type(4)));

__device__ inline unsigned short f2bf(float f) {   // RNE f32->bf16 (finite inputs)
    unsigned u = __float_as_uint(f);
    return (unsigned short)((u + 0x7fffu + ((u >> 16) & 1u)) >> 16);
}

__device__ inline void acc8(const uint4 u, float* a) {  // 8 bf16 -> fp32 accumulate
    a[0] += __uint_as_float(u.x << 16);
    a[1] += __uint_as_float(u.x & 0xffff0000u);
    a[2] += __uint_as_float(u.y << 16);
    a[3] += __uint_as_float(u.y & 0xffff0000u);
    a[4] += __uint_as_float(u.z << 16);
    a[5] += __uint_as_float(u.z & 0xffff0000u);
    a[6] += __uint_as_float(u.w << 16);
    a[7] += __uint_as_float(u.w & 0xffff0000u);
}

// ---------- bucket scatter + inlined prep (xb/whi conversion) ----------
// 512 thr. Grid-stride conversion work runs before the per-block scatter.
// Cursors are RELATIVE (zero-initialized by hipMemsetAsync).

__global__ __launch_bounds__(512) void bucket_scatter_kernel(const int* __restrict__ src,
                                                             const int* __restrict__ dst,
                                                             int* __restrict__ bucketCursor,
                                                             unsigned* __restrict__ bucketData,
                                                             const float* __restrict__ x,
                                                             unsigned short* __restrict__ xb,
                                                             const float* __restrict__ W1_l,
                                                             const float* __restrict__ W1_r,
                                                             const float* __restrict__ W2_l,
                                                             const float* __restrict__ W2_r,
                                                             unsigned short* __restrict__ whi1,
                                                             unsigned short* __restrict__ whi2,
                                                             int E, int NB, int total4) {
    __shared__ int hist[MAXNB];
    __shared__ int lofs[MAXNB];
    __shared__ int lcur[MAXNB];
    __shared__ int gbase[MAXNB];
    __shared__ int sscan[512];
    __shared__ unsigned staged[EPB];   // records sorted by bucket
    __shared__ int gaddr[EPB];         // precomputed global position (-1 = drop)
    const int t = threadIdx.x;
    const int gid = blockIdx.x * 512 + t;
    const int gthreads = gridDim.x * 512;

    // ---- inlined prep: x->bf16, weight prepack (grid-stride) ----
    for (int i = gid; i < total4; i += gthreads) {
        const float4 v = reinterpret_cast<const float4*>(x)[i];
        ushort4 o;
        o.x = f2bf(v.x); o.y = f2bf(v.y); o.z = f2bf(v.z); o.w = f2bf(v.w);
        reinterpret_cast<ushort4*>(xb)[i] = o;
    }
    for (int i = gid; i < 64 * 64; i += gthreads) {      // whi1 [o][k], K=64
        const int o = i >> 6, k = i & 63;
        const float v = (k < 32) ? W1_l[o * 32 + k] : W1_r[o * 32 + (k - 32)];
        whi1[i] = f2bf(v);
    }
    for (int i = gid; i < 64 * 128; i += gthreads) {     // whi2 [o][k], K=128
        const int o = i >> 7, k = i & 127;
        const float v = (k < 64) ? W2_l[o * 64 + k] : W2_r[o * 64 + (k - 64)];
        whi2[i] = f2bf(v);
    }

    // ---- scatter phase ----
    for (int i = t; i < MAXNB; i += 512) hist[i] = 0;
    __syncthreads();
    const int eBase = blockIdx.x * EPB + t;
    int bkt[8]; unsigned rec[8];
#pragma unroll
    for (int j = 0; j < 8; ++j) {
        const int e = eBase + j * 512;
        if (e < E) {
            const int d = dst[e];
            bkt[j] = d >> BSHIFT;
            rec[j] = ((unsigned)src[e] << BSHIFT) | (unsigned)(d & (BNODES - 1));
            atomicAdd(&hist[bkt[j]], 1);
        } else {
            bkt[j] = -1;
        }
    }
    __syncthreads();
    // exclusive scan of hist[0..1024) with 512 threads (2 entries each)
    const int b2 = t * 2;
    const int h0 = hist[b2], h1 = hist[b2 + 1];
    const int tsum = h0 + h1;
    sscan[t] = tsum;
    __syncthreads();
    for (int off = 1; off < 512; off <<= 1) {
        const int v = (t >= off) ? sscan[t - off] : 0;
        __syncthreads();
        sscan[t] += v;
        __syncthreads();
    }
    const int excl = sscan[t] - tsum;
    lofs[b2]     = excl;
    lofs[b2 + 1] = excl + h0;
    lcur[b2]     = excl;
    lcur[b2 + 1] = excl + h0;
    // reserve global runs (relative cursors; one atomic per non-empty bucket)
    for (int bb = t; bb < NB; bb += 512)
        if (hist[bb] > 0) gbase[bb] = atomicAdd(&bucketCursor[bb], hist[bb]);
    __syncthreads();
    // place into bucket-sorted LDS order, precompute global addresses
#pragma unroll
    for (int j = 0; j < 8; ++j) {
        if (bkt[j] >= 0) {
            const int b = bkt[j];
            const int lp = atomicAdd(&lcur[b], 1);
            staged[lp] = rec[j];
            const int rel = gbase[b] + (lp - lofs[b]);
            gaddr[lp] = (rel < BCAP) ? (b * BCAP + rel) : -1;  // overflow guard
        }
    }
    __syncthreads();
    // writeout in sorted order: consecutive i -> consecutive addrs within runs
    const int cnt = min(EPB, E - blockIdx.x * EPB);
    for (int i = t; i < cnt; i += 512) {
        const int p = gaddr[i];
        if (p >= 0) bucketData[p] = staged[i];
    }
}

// 512-thr, one block per bucket: region staged in LDS, counting-sort by
// dstLocal in LDS, csr_src written as one sequential coalesced stream.
// LDS ~39KB -> 4 blocks/CU -> 782 blocks in a single round.
__global__ __launch_bounds__(512) void csr_build_kernel(const unsigned* __restrict__ bucketData,
                                                        const int* __restrict__ bucketCursor,
                                                        int* __restrict__ offs,
                                                        int* __restrict__ offe,
                                                        int* __restrict__ csr_src,
                                                        int N) {
    __shared__ unsigned ldsIn[BCAP];    // 18KB
    __shared__ unsigned ldsOut[BCAP];   // 18KB
    __shared__ int cnt[BNODES];
    __shared__ int sscan[BNODES];
    __shared__ int cur[BNODES];
    const int t   = threadIdx.x;
    const int bkt = blockIdx.x;
    const int nodeBase = bkt << BSHIFT;
    const int regionBase = bkt * BCAP;
    const int count = min(bucketCursor[bkt], BCAP);   // relative cursor = count
    if (t < BNODES) cnt[t] = 0;
    __syncthreads();
    // stage region (coalesced read) + histogram from LDS
    for (int k = t; k < count; k += 512) {
        const unsigned v = bucketData[regionBase + k];
        ldsIn[k] = v;
        atomicAdd(&cnt[v & (BNODES - 1)], 1);
    }
    __syncthreads();
    int v0 = 0;
    if (t < BNODES) { v0 = cnt[t]; sscan[t] = v0; }
    __syncthreads();
    for (int off = 1; off < BNODES; off <<= 1) {
        int v = 0;
        if (t < BNODES && t >= off) v = sscan[t - off];
        __syncthreads();
        if (t < BNODES) sscan[t] += v;
        __syncthreads();
    }
    if (t < BNODES) {
        const int excl = sscan[t] - v0;
        cur[t] = excl;
        const int node = nodeBase + t;
        if (node < N) {
            offs[node] = regionBase + excl;
            offe[node] = regionBase + excl + v0;
        }
    }
    __syncthreads();
    // counting-sort scatter inside LDS
    for (int k = t; k < count; k += 512) {
        const unsigned v = ldsIn[k];
        const int p = atomicAdd(&cur[v & (BNODES - 1)], 1);
        ldsOut[p] = v >> BSHIFT;
    }
    __syncthreads();
    // sequential coalesced write
    for (int k = t; k < count; k += 512)
        csr_src[regionBase + k] = (int)ldsOut[k];
}

// ---------- layer 1: persistent per-WAVE fused gather + MFMA (DIN=32) ----------
// Each wave strides over 16-row tiles; zero barriers anywhere. LDS rows are
// wave-private; per-wave DS ops are in-order, lgkmcnt(0) syncs write->read.

template <int DIN>
__launch_bounds__(256)
__global__ void fused_l1_kernel(const unsigned short* __restrict__ featb,
                                const unsigned short* __restrict__ whi,
                                const float* __restrict__ bias,
                                const int* __restrict__ csr_src,
                                const int* __restrict__ offs,
                                const int* __restrict__ offe,
                                unsigned short* __restrict__ houtb,
                                int N, int nSteps) {
    constexpr int K   = 2 * DIN;      // 64
    constexpr int STR = K + 8;        // 72
    constexpr int D8  = DIN / 8;      // 4
    __shared__ unsigned short A_s[64 * STR];
    const int tid  = threadIdx.x;
    const int lane = tid & 63;
    const int wave = tid >> 6;
    const int rowBase = wave * 16;            // wave-private A_s rows
    const int lr = lane & 15;
    const int q  = lane >> 4;
    const int nWT = (N + 15) >> 4;            // 16-row tiles
    const int wstride = gridDim.x * 4;

    for (int wt = blockIdx.x * 4 + wave; wt < nWT; wt += wstride) {
        const int nodeBase = wt * 16;

        // self features into k [DIN, 2*DIN)
        for (int i = lane; i < 16 * D8; i += 64) {
            const int row = i / D8, qq = i % D8;
            const int n = min(nodeBase + row, N - 1);
            const uint4 u = *reinterpret_cast<const uint4*>(featb + (size_t)n * DIN + qq * 8);
            *reinterpret_cast<uint4*>(&A_s[(rowBase + row) * STR + DIN + qq * 8]) = u;
        }
        // gather-mean into k [0, DIN): D8 lanes/node, 1 uint4/edge, ONE pass
        {
            const int part = lane % D8;
            const int row  = lane / D8;       // 16 nodes/wave
            const int n = nodeBase + row;
            const uint4* base = reinterpret_cast<const uint4*>(featb);
            unsigned short* dp = &A_s[(rowBase + row) * STR + part * 8];
            if (n < N) {
                const int beg = offs[n];
                const int end = offe[n];
                float a[8] = {0.f, 0.f, 0.f, 0.f, 0.f, 0.f, 0.f, 0.f};
                int k = beg;
                for (; k + 8 <= end; k += 8) {
                    int s[8];
#pragma unroll
                    for (int j = 0; j < 8; ++j) s[j] = csr_src[k + j];
                    uint4 u[8];
#pragma unroll
                    for (int j = 0; j < 8; ++j) u[j] = base[(size_t)s[j] * D8 + part];
#pragma unroll
                    for (int j = 0; j < 8; ++j) acc8(u[j], a);
                }
                for (; k + 4 <= end; k += 4) {
                    const int s0 = csr_src[k + 0];
                    const int s1 = csr_src[k + 1];
                    const int s2 = csr_src[k + 2];
                    const int s3 = csr_src[k + 3];
                    const uint4 u0 = base[(size_t)s0 * D8 + part];
                    const uint4 u1 = base[(size_t)s1 * D8 + part];
                    const uint4 u2 = base[(size_t)s2 * D8 + part];
                    const uint4 u3 = base[(size_t)s3 * D8 + part];
                    acc8(u0, a); acc8(u1, a); acc8(u2, a); acc8(u3, a);
                }
                for (; k < end; ++k) {
                    const uint4 u = base[(size_t)csr_src[k] * D8 + part];
                    acc8(u, a);
                }
                const float inv = 1.0f / fmaxf((float)(end - beg), 1.0f);
                ushort4 lo4, hi4;
                lo4.x = f2bf(a[0] * inv); lo4.y = f2bf(a[1] * inv);
                lo4.z = f2bf(a[2] * inv); lo4.w = f2bf(a[3] * inv);
                hi4.x = f2bf(a[4] * inv); hi4.y = f2bf(a[5] * inv);
                hi4.z = f2bf(a[6] * inv); hi4.w = f2bf(a[7] * inv);
                *reinterpret_cast<ushort4*>(dp)     = lo4;
                *reinterpret_cast<ushort4*>(dp + 4) = hi4;
            } else {
                const ushort4 z = {0, 0, 0, 0};
                *reinterpret_cast<ushort4*>(dp)     = z;
                *reinterpret_cast<ushort4*>(dp + 4) = z;
            }
        }

        // wave-sync (rows wave-private); sched_barrier pins ordering (rule 18)
        asm volatile("s_waitcnt lgkmcnt(0)" ::: "memory");
        __builtin_amdgcn_sched_barrier(0);

        f32x4 acc[4];
#pragma unroll
        for (int t4 = 0; t4 < 4; ++t4) {
            const float b = bias[t4 * 16 + lr];
            acc[t4] = (f32x4){b, b, b, b};
        }
        const unsigned short* Arow = &A_s[(rowBase + lr) * STR + q * 8];
        const unsigned short* Brow = whi + (size_t)lr * K + q * 8;
        for (int s = 0; s < nSteps; ++s) {
            const bf16x8 af = *reinterpret_cast<const bf16x8*>(Arow + s * 32);
#pragma unroll
            for (int t4 = 0; t4 < 4; ++t4) {
                const bf16x8 bh = *reinterpret_cast<const bf16x8*>(
                    Brow + (size_t)t4 * 16 * K + s * 32);
                acc[t4] = __builtin_amdgcn_mfma_f32_16x16x32_bf16(af, bh, acc[t4], 0, 0, 0);
            }
        }
        for (int reg = 0; reg < 4; ++reg) {
            const int n = nodeBase + q * 4 + reg;
            if (n >= N) break;
#pragma unroll
            for (int t4 = 0; t4 < 4; ++t4)
                houtb[(size_t)n * 64 + t4 * 16 + lr] = f2bf(fmaxf(acc[t4][reg], 0.0f));
        }
    }
}

// ---------- layer 2: wave-autonomous fused gather + MFMA + pool (R33 exact) ----
// Non-persistent: one 64-node tile per block; grid backfill overlaps tails.

template <int DIN, bool POOL>
__launch_bounds__(256)
__global__ void fused_agg_mfma_kernel(const unsigned short* __restrict__ featb,
                                      const unsigned short* __restrict__ whi,
                                      const float* __restrict__ bias,
                                      const int* __restrict__ csr_src,
                                      const int* __restrict__ offs,
                                      const int* __restrict__ offe,
                                      unsigned short* __restrict__ houtb,
                                      const int* __restrict__ batch,
                                      float* __restrict__ pool_sum,
                                      int N, int nSteps) {
    constexpr int K     = 2 * DIN;    // 128
    constexpr int STR   = K + 8;      // 136 ushorts, rows 16B-aligned
    constexpr int D8    = DIN / 8;    // 8
    constexpr int NPW   = 64 / D8;    // 8 nodes per wave pass
    constexpr int NPASS = 16 / NPW;   // 2
    __shared__ unsigned short A_s[64 * STR];
    __shared__ float poolLds[POOL ? 16 * 65 : 1];   // [graph-row][ch]
    const int tid  = threadIdx.x;
    const int lane = tid & 63;
    const int wave = tid >> 6;
    const int nodeBase = blockIdx.x * 64;
    const int rowBase  = wave * 16;           // wave-owned A_s rows

    if (POOL) {
        for (int i = tid; i < 16 * 65; i += 256) poolLds[i] = 0.0f;
        __syncthreads();   // cheap: pre-gather, all waves arrive together
    }

    // ---- per-wave: self features into k [DIN, 2*DIN) of rows [rowBase,+16) ----
    for (int i = lane; i < 16 * D8; i += 64) {
        const int row = rowBase + i / D8, q = i % D8;
        const int n = min(nodeBase + row, N - 1);
        const uint4 u = *reinterpret_cast<const uint4*>(featb + (size_t)n * DIN + q * 8);
        *reinterpret_cast<uint4*>(&A_s[row * STR + DIN + q * 8]) = u;
    }

    // ---- per-wave: gather-mean into k [0, DIN): D8 lanes/node, 1 uint4/edge ----
    {
        const int part = lane % D8;
        const uint4* base = reinterpret_cast<const uint4*>(featb);
#pragma unroll
        for (int pass = 0; pass < NPASS; ++pass) {
            const int row = rowBase + pass * NPW + lane / D8;
            const int n = nodeBase + row;
            unsigned short* dp = &A_s[row * STR + part * 8];
            if (n < N) {
                const int beg = offs[n];
                const int end = offe[n];
                float a[8] = {0.f, 0.f, 0.f, 0.f, 0.f, 0.f, 0.f, 0.f};
                int k = beg;
                for (; k + 8 <= end; k += 8) {       // 8 uint4 in flight
                    int s[8];
#pragma unroll
                    for (int j = 0; j < 8; ++j) s[j] = csr_src[k + j];
                    uint4 u[8];
#pragma unroll
                    for (int j = 0; j < 8; ++j) u[j] = base[(size_t)s[j] * D8 + part];
#pragma unroll
                    for (int j = 0; j < 8; ++j) acc8(u[j], a);
                }
                for (; k + 4 <= end; k += 4) {
                    const int s0 = csr_src[k + 0];
                    const int s1 = csr_src[k + 1];
                    const int s2 = csr_src[k + 2];
                    const int s3 = csr_src[k + 3];
                    const uint4 u0 = base[(size_t)s0 * D8 + part];
                    const uint4 u1 = base[(size_t)s1 * D8 + part];
                    const uint4 u2 = base[(size_t)s2 * D8 + part];
                    const uint4 u3 = base[(size_t)s3 * D8 + part];
                    acc8(u0, a); acc8(u1, a); acc8(u2, a); acc8(u3, a);
                }
                for (; k < end; ++k) {
                    const uint4 u = base[(size_t)csr_src[k] * D8 + part];
                    acc8(u, a);
                }
                const float inv = 1.0f / fmaxf((float)(end - beg), 1.0f);
                ushort4 lo4, hi4;
                lo4.x = f2bf(a[0] * inv); lo4.y = f2bf(a[1] * inv);
                lo4.z = f2bf(a[2] * inv); lo4.w = f2bf(a[3] * inv);
                hi4.x = f2bf(a[4] * inv); hi4.y = f2bf(a[5] * inv);
                hi4.z = f2bf(a[6] * inv); hi4.w = f2bf(a[7] * inv);
                *reinterpret_cast<ushort4*>(dp)     = lo4;
                *reinterpret_cast<ushort4*>(dp + 4) = hi4;
            } else {
                const ushort4 z = {0, 0, 0, 0};
                *reinterpret_cast<ushort4*>(dp)     = z;
                *reinterpret_cast<ushort4*>(dp + 4) = z;
            }
        }
    }

    // wave-sync: drain this wave's LDS writes before its ds_reads (no block
    // barrier -- rows are wave-private). sched_barrier pins ordering (rule 18).
    asm volatile("s_waitcnt lgkmcnt(0)" ::: "memory");
    __builtin_amdgcn_sched_barrier(0);

    const int lr = lane & 15;        // A: m (node); B: n (out); D: col (out)
    const int q  = lane >> 4;        // frag k-quad; D row group
    f32x4 acc[4];
#pragma unroll
    for (int t = 0; t < 4; ++t) {
        const float b = bias[t * 16 + lr];
        acc[t] = (f32x4){b, b, b, b};
    }
    const unsigned short* Arow = &A_s[(rowBase + lr) * STR + q * 8];
    const unsigned short* Brow = whi + (size_t)lr * K + q * 8;   // + t*16*K + s*32
    for (int s = 0; s < nSteps; ++s) {    // runtime: no full unroll (R11)
        const bf16x8 af = *reinterpret_cast<const bf16x8*>(Arow + s * 32);
#pragma unroll
        for (int t = 0; t < 4; ++t) {
            const bf16x8 bh = *reinterpret_cast<const bf16x8*>(
                Brow + (size_t)t * 16 * K + s * 32);
            acc[t] = __builtin_amdgcn_mfma_f32_16x16x32_bf16(af, bh, acc[t], 0, 0, 0);
        }
    }

    // D layout: row(node local 16) = q*4 + reg, col(out) = t*16 + lr
    if (POOL) {
        const int g0 = batch[nodeBase];
        float ag[4] = {0.f, 0.f, 0.f, 0.f};
        int gcur = -1;
        auto flush_run = [&](int g) {
            const int r = g - g0;
            if (r < 16) {
#pragma unroll
                for (int t = 0; t < 4; ++t)
                    atomicAdd(&poolLds[r * 65 + t * 16 + lr], ag[t]);
            } else {       // statistically never (graphs avg ~50 nodes)
#pragma unroll
                for (int t = 0; t < 4; ++t)
                    atomicAdd(&pool_sum[(size_t)g * 64 + t * 16 + lr], ag[t]);
            }
        };
        for (int reg = 0; reg < 4; ++reg) {
            const int n = nodeBase + rowBase + q * 4 + reg;
            if (n >= N) break;
            const int g = batch[n];              // sorted
            if (g != gcur) {
                if (gcur >= 0) flush_run(gcur);
                gcur = g;
                ag[0] = ag[1] = ag[2] = ag[3] = 0.f;
            }
#pragma unroll
            for (int t = 0; t < 4; ++t)
                ag[t] += fmaxf(acc[t][reg], 0.0f);
        }
        if (gcur >= 0) flush_run(gcur);
        __syncthreads();
        // flush: interior rows sole-writer -> plain store (pool pre-zeroed);
        // boundary rows (r==0, r==S-1) -> global atomicAdd.
        const int glast = batch[min(nodeBase + 63, N - 1)];
        const int S = min(glast - g0 + 1, 16);
        for (int i = tid; i < S * 64; i += 256) {
            const int r = i >> 6, c = i & 63;
            const float v = poolLds[r * 65 + c];
            float* dstp = &pool_sum[(size_t)(g0 + r) * 64 + c];
            if (r == 0 || r == S - 1) atomicAdd(dstp, v);
            else *dstp = v;
        }
    } else {
        for (int reg = 0; reg < 4; ++reg) {
            const int n = nodeBase + rowBase + q * 4 + reg;
            if (n >= N) break;
#pragma unroll
            for (int t = 0; t < 4; ++t)
                houtb[(size_t)n * 64 + t * 16 + lr] = f2bf(fmaxf(acc[t][reg], 0.0f));
        }
    }
}

// ---------- head: per-graph count via binary search over sorted batch ----------

__device__ inline int lower_bound_batch(const int* __restrict__ batch, int N, int key) {
    int lo = 0, hi = N;
    while (lo < hi) {
        const int mid = (lo + hi) >> 1;
        if (batch[mid] < key) lo = mid + 1; else hi = mid;
    }
    return lo;
}

__global__ void final_kernel(const float* __restrict__ pool_sum,
                             const int* __restrict__ batch,
                             const float* __restrict__ W_lin,
                             const float* __restrict__ b_lin,
                             float* __restrict__ out, int G, int N) {
    int t = blockIdx.x * blockDim.x + threadIdx.x;
    if (t >= G * 2) return;
    int g = t >> 1, o = t & 1;
    const int c0 = lower_bound_batch(batch, N, g);
    const int c1 = lower_bound_batch(batch, N, g + 1);
    float inv = 1.0f / fmaxf((float)(c1 - c0), 1.0f);
    float acc = b_lin[o];
#pragma unroll
    for (int c = 0; c < 64; ++c)
        acc = fmaf(pool_sum[(size_t)g * 64 + c] * inv, W_lin[o * 64 + c], acc);
    out[t] = acc;
}

extern "C" void kernel_launch(void* const* d_in, const int* in_sizes, int n_in,
                              void* d_out, int out_size, void* d_ws, size_t ws_size,
                              hipStream_t stream) {
    const float* x     = (const float*)d_in[0];
    const int*   ei    = (const int*)d_in[1];
    const int*   batch = (const int*)d_in[2];
    const float* W1_l  = (const float*)d_in[3];
    const float* b1    = (const float*)d_in[4];
    const float* W1_r  = (const float*)d_in[5];
    const float* W2_l  = (const float*)d_in[6];
    const float* b2    = (const float*)d_in[7];
    const float* W2_r  = (const float*)d_in[8];
    const float* W_lin = (const float*)d_in[9];
    const float* b_lin = (const float*)d_in[10];

    const int N = in_sizes[0] / 32;
    const int E = in_sizes[1] / 2;
    const int G = out_size / 2;
    const int* src = ei;
    const int* dst = ei + E;
    const int NB = (N + BNODES - 1) >> BSHIFT;   // 782 for N=200000

    char* p = (char*)d_ws;
    auto carve = [&](size_t bytes) -> void* {
        void* r = (void*)p;
        p += (bytes + (WS_ALIGN - 1)) / WS_ALIGN * WS_ALIGN;
        return r;
    };
    int*            bucketCursor = (int*)carve((size_t)MAXNB * 4);
    unsigned*       bucketData   = (unsigned*)carve((size_t)NB * BCAP * 4);
    int*            offs         = (int*)carve((size_t)N * 4);
    int*            offe         = (int*)carve((size_t)N * 4);
    int*            csr_src      = (int*)carve((size_t)NB * BCAP * 4);
    unsigned short* xb           = (unsigned short*)carve((size_t)N * 32 * 2);
    unsigned short* h1b          = (unsigned short*)carve((size_t)N * 64 * 2);
    unsigned short* whi1         = (unsigned short*)carve(64 * 64 * 2);
    unsigned short* whi2         = (unsigned short*)carve(64 * 128 * 2);
    float*          pool         = (float*)carve((size_t)G * 64 * 4);
    float*          out          = (float*)d_out;

    const int TB = 256;
    const int total4 = N * 32 / 4;

    // zero relative cursors + pool (replaces prep_kernel's init work)
    hipMemsetAsync(bucketCursor, 0, (size_t)MAXNB * 4, stream);
    hipMemsetAsync(pool, 0, (size_t)G * 64 * 4, stream);

    // scatter + inlined xb/whi conversion
    bucket_scatter_kernel<<<(E + EPB - 1) / EPB, 512, 0, stream>>>(
        src, dst, bucketCursor, bucketData,
        x, xb, W1_l, W1_r, W2_l, W2_r, whi1, whi2, E, NB, total4);
    csr_build_kernel<<<NB, 512, 0, stream>>>(bucketData, bucketCursor, offs, offe, csr_src, N);

    // layer 1: persistent per-wave fused gather + MFMA 32->64 + relu -> h1b
    const int nWT = (N + 15) >> 4;
    const int grid1 = min(2048, (nWT + 3) / 4);
    fused_l1_kernel<32><<<grid1, TB, 0, stream>>>(
        xb, whi1, b1, csr_src, offs, offe, h1b, N, 2);

    // layer 2: non-persistent wave-autonomous fused gather + MFMA + pool (R33)
    fused_agg_mfma_kernel<64, true><<<(N + 63) / 64, TB, 0, stream>>>(
        h1b, whi2, b2, csr_src, offs, offe, nullptr, batch, pool, N, 4);

    final_kernel<<<(G * 2 + TB - 1) / TB, TB, 0, stream>>>(pool, batch, W_lin, b_lin,
                                                           out, G, N);
}